// Round 9
// baseline (253.589 us; speedup 1.0000x reference)
//
#include <hip/hip_runtime.h>
#include <hip/hip_bf16.h>
#include <math.h>

// Problem constants
#define NN 30000
#define NE 480000
#define FIN 256
#define DH 32
#define NH 4
#define NC 47
#define NODE_BLKS 7500   // NN/4 (4 waves/block, 1 wave/node)
#define EDGE_BLKS 1875   // NE/256

typedef __attribute__((ext_vector_type(8))) short frag_ab;  // 8 bf16 (4 VGPR)
typedef __attribute__((ext_vector_type(4))) float f32x4;    // MFMA 16x16 accum
typedef __hip_bfloat16 bf16;

static inline size_t align256(size_t x) { return (x + 255) & ~(size_t)255; }

__device__ __forceinline__ short f2bf(float f) {
    union { float f; unsigned u; } c; c.f = f;
    unsigned r = (c.u + 0x7FFFu + ((c.u >> 16) & 1u)) >> 16;  // RNE
    return (short)r;
}
__device__ __forceinline__ float b2f(unsigned short u) {
    union { unsigned u; float f; } c; c.u = (unsigned)u << 16; return c.f;
}
// exp(leaky_relu(v)) — no max subtraction (scores O(10), far from f32 overflow)
__device__ __forceinline__ float expw(float v) {
    return __expf((v >= 0.f) ? v : 0.2f * v);
}
__device__ __forceinline__ float lrelu(float v) {
    return (v >= 0.f) ? v : 0.2f * v;
}

// ---------------- CSR build ----------------
__global__ void count_k(const int* __restrict__ dst, int* __restrict__ cnt, int E) {
    int e = blockIdx.x * blockDim.x + threadIdx.x;
    if (e < E) atomicAdd(&cnt[dst[e]], 1);
}

// exclusive scan; writes offs[0..n] AND cursor[0..n-1] (fill cursors)
__global__ __launch_bounds__(1024) void scan_k(const int* __restrict__ cnt,
                                               int* __restrict__ offs,
                                               int* __restrict__ cursor, int n) {
    __shared__ int warp_sums[16];
    __shared__ int carry_s;
    const int lane = threadIdx.x & 63;
    const int wid = threadIdx.x >> 6;
    if (threadIdx.x == 0) carry_s = 0;
    __syncthreads();
    for (int base = 0; base < n; base += 1024) {
        int i = base + threadIdx.x;
        int v = (i < n) ? cnt[i] : 0;
        int x = v;
        #pragma unroll
        for (int off = 1; off < 64; off <<= 1) {
            int y = __shfl_up(x, off);
            if (lane >= off) x += y;
        }
        if (lane == 63) warp_sums[wid] = x;
        __syncthreads();
        if (wid == 0) {
            int ws = (lane < 16) ? warp_sums[lane] : 0;
            #pragma unroll
            for (int off = 1; off < 16; off <<= 1) {
                int y = __shfl_up(ws, off);
                if (lane >= off) ws += y;
            }
            if (lane < 16) warp_sums[lane] = ws;
        }
        __syncthreads();
        int wbase = (wid > 0) ? warp_sums[wid - 1] : 0;
        int incl = x + wbase + carry_s;
        if (i < n) {
            offs[i] = incl - v;  // exclusive
            cursor[i] = incl - v;
        }
        __syncthreads();
        if (threadIdx.x == 1023) carry_s = incl;
        __syncthreads();
    }
    if (threadIdx.x == 0) offs[n] = carry_s;
}

// srcs[slot] = src id, in CSR-by-dst order
__global__ void fill_k(const int* __restrict__ dst, const int* __restrict__ src,
                       int* __restrict__ cursor, int* __restrict__ srcs, int E) {
    int e = blockIdx.x * blockDim.x + threadIdx.x;
    if (e < E) {
        int p = atomicAdd(&cursor[dst[e]], 1);
        srcs[p] = src[e];
    }
}

// ---- weight prep (+ cursor zeroing in y==5): transposed bf16 weights with
// fused el/er projection rows. Rows 0..M-1 = W^T; M..M+H-1 = W·al; M+H..M+2H-1 = W·ar.
__global__ void prep_w_all(const float* __restrict__ W0, const float* __restrict__ W1,
                           const float* __restrict__ rW1, const float* __restrict__ W2,
                           const float* __restrict__ rW2,
                           const float* __restrict__ al0, const float* __restrict__ ar0,
                           const float* __restrict__ al1, const float* __restrict__ ar1,
                           const float* __restrict__ al2, const float* __restrict__ ar2,
                           bf16* __restrict__ W0t, bf16* __restrict__ W1t,
                           bf16* __restrict__ rW1t, bf16* __restrict__ W2t,
                           bf16* __restrict__ rW2t, int* __restrict__ cursor) {
    if (blockIdx.y == 5) {
        int i = blockIdx.x * 256 + threadIdx.x;
        if (i < NN) cursor[i] = 0;
        return;
    }
    const float *W, *al, *ar; bf16* Wt; int K, M, rows, H, D;
    switch (blockIdx.y) {
        case 0: W = W0;  Wt = W0t;  K = 256; M = 128; rows = 144; H = 4; D = 32; al = al0; ar = ar0; break;
        case 1: W = W1;  Wt = W1t;  K = 128; M = 128; rows = 144; H = 4; D = 32; al = al1; ar = ar1; break;
        case 2: W = rW1; Wt = rW1t; K = 128; M = 128; rows = 128; H = 0; D = 0;  al = nullptr; ar = nullptr; break;
        case 3: W = W2;  Wt = W2t;  K = 128; M = 47;  rows = 64;  H = 1; D = 47; al = al2; ar = ar2; break;
        default: W = rW2; Wt = rW2t; K = 128; M = 47; rows = 48;  H = 0; D = 0;  al = nullptr; ar = nullptr; break;
    }
    int i = blockIdx.x * 256 + threadIdx.x;
    if (i >= rows * K) return;
    int row = i / K, k = i - row * K;
    float v = 0.f;
    if (row < M) {
        v = W[(long)k * M + row];
    } else if (H > 0 && row < M + 2 * H) {
        int idx = row - M;
        int h = (idx < H) ? idx : idx - H;
        const float* a = (idx < H) ? al : ar;
        float s = 0.f;
        for (int d = 0; d < D; ++d) s += W[(long)k * M + h * D + d] * a[h * D + d];
        v = s;
    }
    Wt[i] = __float2bfloat16(v);
}

// ---- bf16 MFMA GEMM + fused attn projections ----
template <bool A_F32, int NT1, int NT2, int HH>
__global__ __launch_bounds__(256) void gemm_mfma(
    const void* __restrict__ Av, const bf16* __restrict__ B1t,
    const bf16* __restrict__ B2t,
    bf16* __restrict__ C1b, float* __restrict__ el, float* __restrict__ er,
    float* __restrict__ C2, int N, int K, int M) {
    constexpr int LP = 56;  // 32 k + pad: rows 112B (16B-aligned, 2-way alias = free)
    __shared__ bf16 As[64][LP];
    __shared__ bf16 Bs1[NT1 * 16][LP];
    __shared__ bf16 Bs2[(NT2 > 0) ? NT2 * 16 : 1][LP];

    const int tid = threadIdx.x;
    const int lane = tid & 63;
    const int wid = tid >> 6;
    const int row0 = blockIdx.x * 64;
    const int l15 = lane & 15;
    const int kq = lane >> 4;          // k-quarter 0..3

    f32x4 acc1[NT1], acc2[(NT2 > 0) ? NT2 : 1];
    #pragma unroll
    for (int t = 0; t < NT1; ++t) acc1[t] = (f32x4){0.f, 0.f, 0.f, 0.f};
    if constexpr (NT2 > 0) {
        #pragma unroll
        for (int t = 0; t < NT2; ++t) acc2[t] = (f32x4){0.f, 0.f, 0.f, 0.f};
    }

    for (int k0 = 0; k0 < K; k0 += 32) {
        {
            const int r = tid >> 2, kk = (tid & 3) * 8;
            const int gr = row0 + r;
            if constexpr (A_F32) {
                const float* A = (const float*)Av;
                short tmp[8];
                if (gr < N) {
                    const float4 v0 = *(const float4*)&A[(long)gr * K + k0 + kk];
                    const float4 v1 = *(const float4*)&A[(long)gr * K + k0 + kk + 4];
                    tmp[0] = f2bf(v0.x); tmp[1] = f2bf(v0.y); tmp[2] = f2bf(v0.z); tmp[3] = f2bf(v0.w);
                    tmp[4] = f2bf(v1.x); tmp[5] = f2bf(v1.y); tmp[6] = f2bf(v1.z); tmp[7] = f2bf(v1.w);
                } else {
                    #pragma unroll
                    for (int j = 0; j < 8; ++j) tmp[j] = 0;
                }
                *(frag_ab*)&As[r][kk] = *(const frag_ab*)tmp;
            } else {
                const bf16* A = (const bf16*)Av;
                frag_ab v = {0, 0, 0, 0, 0, 0, 0, 0};
                if (gr < N) v = *(const frag_ab*)&A[(long)gr * K + k0 + kk];
                *(frag_ab*)&As[r][kk] = v;
            }
        }
        for (int i = tid; i < NT1 * 64; i += 256) {
            const int c = i >> 2, kk = (i & 3) * 8;
            *(frag_ab*)&Bs1[c][kk] = *(const frag_ab*)&B1t[(long)c * K + k0 + kk];
        }
        if constexpr (NT2 > 0) {
            for (int i = tid; i < NT2 * 64; i += 256) {
                const int c = i >> 2, kk = (i & 3) * 8;
                *(frag_ab*)&Bs2[c][kk] = *(const frag_ab*)&B2t[(long)c * K + k0 + kk];
            }
        }
        __syncthreads();

        const frag_ab a = *(const frag_ab*)&As[wid * 16 + l15][kq * 8];
        #pragma unroll
        for (int t = 0; t < NT1; ++t) {
            const frag_ab b = *(const frag_ab*)&Bs1[t * 16 + l15][kq * 8];
            acc1[t] = __builtin_amdgcn_mfma_f32_16x16x32_bf16(a, b, acc1[t], 0, 0, 0);
        }
        if constexpr (NT2 > 0) {
            #pragma unroll
            for (int t = 0; t < NT2; ++t) {
                const frag_ab b = *(const frag_ab*)&Bs2[t * 16 + l15][kq * 8];
                acc2[t] = __builtin_amdgcn_mfma_f32_16x16x32_bf16(a, b, acc2[t], 0, 0, 0);
            }
        }
        __syncthreads();
    }

    const int r0 = row0 + wid * 16 + kq * 4;
    #pragma unroll
    for (int t = 0; t < NT1; ++t) {
        const int c = t * 16 + l15;
        #pragma unroll
        for (int reg = 0; reg < 4; ++reg) {
            const int r = r0 + reg;
            if (r >= N) continue;
            const float v = acc1[t][reg];
            if (c < M) {
                C1b[(long)r * M + c] = __float2bfloat16(v);
            } else if (c < M + HH) {
                el[(long)r * HH + (c - M)] = v;
            } else if (c < M + 2 * HH) {
                er[(long)r * HH + (c - M - HH)] = v;
            }
        }
    }
    if constexpr (NT2 > 0) {
        #pragma unroll
        for (int t = 0; t < NT2; ++t) {
            const int c = t * 16 + l15;
            if (c >= M) continue;
            #pragma unroll
            for (int reg = 0; reg < 4; ++reg) {
                const int r = r0 + reg;
                if (r < N) C2[(long)r * M + c] = acc2[t][reg];
            }
        }
    }
}

// ---- node softmax + aggregation, one wave/node, H=4 D=32 (HD=128) ----
// Phase A (lane-strided): t = exp(lrelu(el[src]+er[node])) per edge, s += t;
//   first 64 edges cached in LDS (deg<=64 in practice), rest spill to global es.
// Phase B (half-wave per edge): 32 lanes x ushort4 row gather, 2 edges in flight.
template <int NELU, bool HAS_RES>
__global__ __launch_bounds__(256) void node_agg4(
    const bf16* __restrict__ featb, const float4* __restrict__ el4,
    const float4* __restrict__ er4, float4* __restrict__ es4,
    const int* __restrict__ offs, const int* __restrict__ srcs,
    const float* __restrict__ res, bf16* __restrict__ out) {
    __shared__ float4 sc[4][64];      // per-wave score cache (4 KB)
    const int node = (int)((blockIdx.x * blockDim.x + threadIdx.x) >> 6);
    const int lane = threadIdx.x & 63;
    const int wid = threadIdx.x >> 6;
    const int beg = offs[node], end = offs[node + 1];
    const float4 ern = er4[node];   // wave-uniform

    // phase A
    float4 s4 = make_float4(0.f, 0.f, 0.f, 0.f);
    for (int i = beg + lane; i < end; i += 64) {
        const float4 elv = el4[srcs[i]];
        float4 t;
        t.x = expw(elv.x + ern.x); t.y = expw(elv.y + ern.y);
        t.z = expw(elv.z + ern.z); t.w = expw(elv.w + ern.w);
        s4.x += t.x; s4.y += t.y; s4.z += t.z; s4.w += t.w;
        const int idx = i - beg;
        if (idx < 64) sc[wid][idx] = t;
        else es4[i] = t;
    }
    #pragma unroll
    for (int off = 32; off > 0; off >>= 1) {
        s4.x += __shfl_xor(s4.x, off);
        s4.y += __shfl_xor(s4.y, off);
        s4.z += __shfl_xor(s4.z, off);
        s4.w += __shfl_xor(s4.w, off);
    }
    __syncthreads();   // orders the (rare) global spill stores before phase-B reads

    // phase B: two edges per iteration (half-wave each)
    const int half = lane >> 5;
    const int l31 = lane & 31;
    const int fi = l31 * 4;           // 4 consecutive features
    const int h = l31 >> 3;           // fi / 32
    const float sh = (h == 0) ? s4.x : (h == 1) ? s4.y : (h == 2) ? s4.z : s4.w;
    const float inv = 1.f / fmaxf(sh, 1e-9f);
    const float* esf = (const float*)es4;
    const float* scf = (const float*)sc[wid];

    float a0 = 0.f, a1 = 0.f, a2 = 0.f, a3 = 0.f;
    int i = beg + half;
    for (; i + 2 < end; i += 4) {
        const int iB = i + 2;
        const int idxA = i - beg, idxB = iB - beg;
        const int snA = srcs[i], snB = srcs[iB];
        const float wA = (idxA < 64) ? scf[idxA * 4 + h] : esf[i * 4 + h];
        const float wB = (idxB < 64) ? scf[idxB * 4 + h] : esf[iB * 4 + h];
        const ushort4 fA = *(const ushort4*)(featb + (long)snA * 128 + fi);
        const ushort4 fB = *(const ushort4*)(featb + (long)snB * 128 + fi);
        a0 += wA * b2f(fA.x) + wB * b2f(fB.x);
        a1 += wA * b2f(fA.y) + wB * b2f(fB.y);
        a2 += wA * b2f(fA.z) + wB * b2f(fB.z);
        a3 += wA * b2f(fA.w) + wB * b2f(fB.w);
    }
    for (; i < end; i += 2) {
        const int idx = i - beg;
        const int sn = srcs[i];
        const float w = (idx < 64) ? scf[idx * 4 + h] : esf[i * 4 + h];
        const ushort4 f = *(const ushort4*)(featb + (long)sn * 128 + fi);
        a0 += w * b2f(f.x); a1 += w * b2f(f.y);
        a2 += w * b2f(f.z); a3 += w * b2f(f.w);
    }
    a0 += __shfl_xor(a0, 32);
    a1 += __shfl_xor(a1, 32);
    a2 += __shfl_xor(a2, 32);
    a3 += __shfl_xor(a3, 32);

    if (lane < 32) {
        float v0 = a0 * inv, v1 = a1 * inv, v2 = a2 * inv, v3 = a3 * inv;
        if constexpr (HAS_RES) {
            const float4 rr = *(const float4*)(res + (long)node * 128 + fi);
            v0 += rr.x; v1 += rr.y; v2 += rr.z; v3 += rr.w;
        }
        #pragma unroll
        for (int t = 0; t < NELU; ++t) {
            v0 = (v0 > 0.f) ? v0 : expm1f(v0);
            v1 = (v1 > 0.f) ? v1 : expm1f(v1);
            v2 = (v2 > 0.f) ? v2 : expm1f(v2);
            v3 = (v3 > 0.f) ? v3 : expm1f(v3);
        }
        ushort4 o;
        o.x = (unsigned short)f2bf(v0); o.y = (unsigned short)f2bf(v1);
        o.z = (unsigned short)f2bf(v2); o.w = (unsigned short)f2bf(v3);
        *(ushort4*)(out + (long)node * 128 + fi) = o;
    }
}

// ---- final fused kernel: node_agg1 (blocks < NODE_BLKS) + all edge-score
// outputs e0/e1/e2 (remaining blocks; reads src/dst once for all 3 layers) ----
__global__ __launch_bounds__(256) void final_k(
    const bf16* __restrict__ featb, const float* __restrict__ el2s,
    const float* __restrict__ er2s, float* __restrict__ es1,
    const int* __restrict__ offs, const int* __restrict__ srcs,
    const float* __restrict__ res, float* __restrict__ logits,
    const float4* __restrict__ el0, const float4* __restrict__ er0,
    const float4* __restrict__ el1, const float4* __restrict__ er1,
    const int* __restrict__ src, const int* __restrict__ dst,
    float* __restrict__ e0, float* __restrict__ e1, float* __restrict__ e2) {
    __shared__ float sc1[4][64];      // per-wave score cache (1 KB)
    if (blockIdx.x < NODE_BLKS) {
        const int node = (int)((blockIdx.x * blockDim.x + threadIdx.x) >> 6);
        const int lane = threadIdx.x & 63;
        const int wid = threadIdx.x >> 6;
        const int beg = offs[node], end = offs[node + 1];
        const float ern = er2s[node];

        float s = 0.f;
        for (int i = beg + lane; i < end; i += 64) {
            const float t = expw(el2s[srcs[i]] + ern);
            s += t;
            const int idx = i - beg;
            if (idx < 64) sc1[wid][idx] = t;
            else es1[i] = t;
        }
        #pragma unroll
        for (int off = 32; off > 0; off >>= 1) s += __shfl_xor(s, off);
        const float inv = 1.f / fmaxf(s, 1e-9f);
        __syncthreads();

        const bool active = lane < NC;
        float acc = 0.f;
        for (int i = beg; i < end; ++i) {
            const int idx = i - beg;
            const float w = (idx < 64) ? sc1[wid][idx] : es1[i];
            if (active) acc += w * __bfloat162float(featb[(long)srcs[i] * NC + lane]);
        }
        if (active) {
            logits[(long)node * NC + lane] = acc * inv + res[(long)node * NC + lane];
        }
    } else {
        const int e = (blockIdx.x - NODE_BLKS) * 256 + threadIdx.x;  // exact NE
        const int s = src[e], d = dst[e];
        const float4 a0 = el0[s], b0 = er0[d];
        float4 v0;
        v0.x = lrelu(a0.x + b0.x); v0.y = lrelu(a0.y + b0.y);
        v0.z = lrelu(a0.z + b0.z); v0.w = lrelu(a0.w + b0.w);
        *reinterpret_cast<float4*>(e0 + e * 4) = v0;
        const float4 a1 = el1[s], b1 = er1[d];
        float4 v1;
        v1.x = lrelu(a1.x + b1.x); v1.y = lrelu(a1.y + b1.y);
        v1.z = lrelu(a1.z + b1.z); v1.w = lrelu(a1.w + b1.w);
        *reinterpret_cast<float4*>(e1 + e * 4) = v1;
        e2[e] = lrelu(el2s[s] + er2s[d]);
    }
}

extern "C" void kernel_launch(void* const* d_in, const int* in_sizes, int n_in,
                              void* d_out, int out_size, void* d_ws, size_t ws_size,
                              hipStream_t stream) {
    const float* x     = (const float*)d_in[0];
    const float* W0    = (const float*)d_in[1];
    const float* al0   = (const float*)d_in[2];
    const float* ar0   = (const float*)d_in[3];
    const float* W1    = (const float*)d_in[4];
    const float* resW1 = (const float*)d_in[5];
    const float* al1   = (const float*)d_in[6];
    const float* ar1   = (const float*)d_in[7];
    const float* W2    = (const float*)d_in[8];
    const float* resW2 = (const float*)d_in[9];
    const float* al2   = (const float*)d_in[10];
    const float* ar2   = (const float*)d_in[11];
    const int*   src   = (const int*)d_in[12];
    const int*   dst   = (const int*)d_in[13];

    float* out    = (float*)d_out;
    float* logits = out;                 // [N, 47]
    float* e0     = out + (long)NN * NC; // [E, 4]
    float* e1     = e0 + (long)NE * NH;  // [E, 4]
    float* e2     = e1 + (long)NE * NH;  // [E, 1]

    char* p = (char*)d_ws;
    int* offs   = (int*)p; p += align256(sizeof(int) * (NN + 1));
    int* cursor = (int*)p; p += align256(sizeof(int) * NN);
    int* srcs   = (int*)p; p += align256(sizeof(int) * NE);
    float* el0b = (float*)p; p += align256(sizeof(float) * NN * NH);
    float* er0b = (float*)p; p += align256(sizeof(float) * NN * NH);
    float* el1b = (float*)p; p += align256(sizeof(float) * NN * NH);
    float* er1b = (float*)p; p += align256(sizeof(float) * NN * NH);
    float* el2b = (float*)p; p += align256(sizeof(float) * NN);
    float* er2b = (float*)p; p += align256(sizeof(float) * NN);
    float* es   = (float*)p; p += align256(sizeof(float) * (long)NE * NH);  // spill fallback
    float* resb = (float*)p; p += align256(sizeof(float) * (long)NN * 128);
    bf16* featb = (bf16*)p; p += align256(sizeof(bf16) * (long)NN * 128);
    bf16* hb    = (bf16*)p; p += align256(sizeof(bf16) * (long)NN * 128);
    bf16* W0t   = (bf16*)p; p += align256(sizeof(bf16) * 144 * 256);
    bf16* W1t   = (bf16*)p; p += align256(sizeof(bf16) * 144 * 128);
    bf16* rW1t  = (bf16*)p; p += align256(sizeof(bf16) * 128 * 128);
    bf16* W2t   = (bf16*)p; p += align256(sizeof(bf16) * 64 * 128);
    bf16* rW2t  = (bf16*)p; p += align256(sizeof(bf16) * 48 * 128);

    // ---- weight prep + cursor zero (y==5) ----
    prep_w_all<<<dim3(144, 6), 256, 0, stream>>>(W0, W1, resW1, W2, resW2,
                                                 al0, ar0, al1, ar1, al2, ar2,
                                                 W0t, W1t, rW1t, W2t, rW2t, cursor);

    // ---- CSR by dst ----
    count_k<<<EDGE_BLKS, 256, 0, stream>>>(dst, cursor, NE);
    scan_k<<<1, 1024, 0, stream>>>(cursor, offs, cursor, NN);
    fill_k<<<EDGE_BLKS, 256, 0, stream>>>(dst, src, cursor, srcs, NE);

    const int gemmBlocks = (NN + 63) / 64;   // 469

    // ---- layer 0: x @ [W0|wl0|wr0] -> featb bf16 + el0 + er0 ----
    gemm_mfma<true, 9, 0, NH><<<gemmBlocks, 256, 0, stream>>>(
        x, W0t, nullptr, featb, el0b, er0b, nullptr, NN, FIN, 128);
    node_agg4<1, false><<<NODE_BLKS, 256, 0, stream>>>(
        featb, (const float4*)el0b, (const float4*)er0b, (float4*)es, offs, srcs, nullptr, hb);

    // ---- layer 1: hb @ [W1|wl1|wr1] + hb @ resW1 -> featb/el1/er1 + resb ----
    gemm_mfma<false, 9, 8, NH><<<gemmBlocks, 256, 0, stream>>>(
        hb, W1t, rW1t, featb, el1b, er1b, resb, NN, 128, 128);
    node_agg4<2, true><<<NODE_BLKS, 256, 0, stream>>>(
        featb, (const float4*)el1b, (const float4*)er1b, (float4*)es, offs, srcs, resb, hb);

    // ---- final layer: hb @ [W2|wl2|wr2] + hb @ resW2 (M=47) ----
    gemm_mfma<false, 4, 3, 1><<<gemmBlocks, 256, 0, stream>>>(
        hb, W2t, rW2t, featb, el2b, er2b, resb, NN, 128, NC);
    // fused: node_agg1 (logits) + e0/e1/e2 edge-score outputs
    final_k<<<NODE_BLKS + EDGE_BLKS, 256, 0, stream>>>(
        featb, el2b, er2b, es, offs, srcs, resb, logits,
        (const float4*)el0b, (const float4*)er0b,
        (const float4*)el1b, (const float4*)er1b,
        src, dst, e0, e1, e2);
}

// Round 10
// 229.291 us; speedup vs baseline: 1.1060x; 1.1060x over previous
//
#include <hip/hip_runtime.h>
#include <hip/hip_bf16.h>
#include <math.h>

// Problem constants
#define NN 30000
#define NE 480000
#define FIN 256
#define DH 32
#define NH 4
#define NC 47
#define NODE_BLKS 7500   // NN/4 (4 waves/block, 1 wave/node)
#define EDGE_BLKS 1875   // NE/256

typedef __attribute__((ext_vector_type(8))) short frag_ab;  // 8 bf16 (4 VGPR)
typedef __attribute__((ext_vector_type(4))) float f32x4;    // MFMA 16x16 accum
typedef __hip_bfloat16 bf16;

static inline size_t align256(size_t x) { return (x + 255) & ~(size_t)255; }

__device__ __forceinline__ short f2bf(float f) {
    union { float f; unsigned u; } c; c.f = f;
    unsigned r = (c.u + 0x7FFFu + ((c.u >> 16) & 1u)) >> 16;  // RNE
    return (short)r;
}
__device__ __forceinline__ float b2f(unsigned short u) {
    union { unsigned u; float f; } c; c.u = (unsigned)u << 16; return c.f;
}
// exp(leaky_relu(v)) — no max subtraction (scores O(10), far from f32 overflow)
__device__ __forceinline__ float expw(float v) {
    return __expf((v >= 0.f) ? v : 0.2f * v);
}
__device__ __forceinline__ float lrelu(float v) {
    return (v >= 0.f) ? v : 0.2f * v;
}

// ---------------- CSR build ----------------
__global__ void count_k(const int* __restrict__ dst, int* __restrict__ cnt, int E) {
    int e = blockIdx.x * blockDim.x + threadIdx.x;
    if (e < E) atomicAdd(&cnt[dst[e]], 1);
}

// exclusive scan; writes offs[0..n] AND cursor[0..n-1] (fill cursors)
__global__ __launch_bounds__(1024) void scan_k(const int* __restrict__ cnt,
                                               int* __restrict__ offs,
                                               int* __restrict__ cursor, int n) {
    __shared__ int warp_sums[16];
    __shared__ int carry_s;
    const int lane = threadIdx.x & 63;
    const int wid = threadIdx.x >> 6;
    if (threadIdx.x == 0) carry_s = 0;
    __syncthreads();
    for (int base = 0; base < n; base += 1024) {
        int i = base + threadIdx.x;
        int v = (i < n) ? cnt[i] : 0;
        int x = v;
        #pragma unroll
        for (int off = 1; off < 64; off <<= 1) {
            int y = __shfl_up(x, off);
            if (lane >= off) x += y;
        }
        if (lane == 63) warp_sums[wid] = x;
        __syncthreads();
        if (wid == 0) {
            int ws = (lane < 16) ? warp_sums[lane] : 0;
            #pragma unroll
            for (int off = 1; off < 16; off <<= 1) {
                int y = __shfl_up(ws, off);
                if (lane >= off) ws += y;
            }
            if (lane < 16) warp_sums[lane] = ws;
        }
        __syncthreads();
        int wbase = (wid > 0) ? warp_sums[wid - 1] : 0;
        int incl = x + wbase + carry_s;
        if (i < n) {
            offs[i] = incl - v;  // exclusive
            cursor[i] = incl - v;
        }
        __syncthreads();
        if (threadIdx.x == 1023) carry_s = incl;
        __syncthreads();
    }
    if (threadIdx.x == 0) offs[n] = carry_s;
}

// srcs[slot] = src id, in CSR-by-dst order
__global__ void fill_k(const int* __restrict__ dst, const int* __restrict__ src,
                       int* __restrict__ cursor, int* __restrict__ srcs, int E) {
    int e = blockIdx.x * blockDim.x + threadIdx.x;
    if (e < E) {
        int p = atomicAdd(&cursor[dst[e]], 1);
        srcs[p] = src[e];
    }
}

// ---- weight prep (+ cursor zeroing in y==5): transposed bf16 weights with
// fused el/er projection rows. Rows 0..M-1 = W^T; M..M+H-1 = W·al; M+H..M+2H-1 = W·ar.
__global__ void prep_w_all(const float* __restrict__ W0, const float* __restrict__ W1,
                           const float* __restrict__ rW1, const float* __restrict__ W2,
                           const float* __restrict__ rW2,
                           const float* __restrict__ al0, const float* __restrict__ ar0,
                           const float* __restrict__ al1, const float* __restrict__ ar1,
                           const float* __restrict__ al2, const float* __restrict__ ar2,
                           bf16* __restrict__ W0t, bf16* __restrict__ W1t,
                           bf16* __restrict__ rW1t, bf16* __restrict__ W2t,
                           bf16* __restrict__ rW2t, int* __restrict__ cursor) {
    if (blockIdx.y == 5) {
        int i = blockIdx.x * 256 + threadIdx.x;
        if (i < NN) cursor[i] = 0;
        return;
    }
    const float *W, *al, *ar; bf16* Wt; int K, M, rows, H, D;
    switch (blockIdx.y) {
        case 0: W = W0;  Wt = W0t;  K = 256; M = 128; rows = 144; H = 4; D = 32; al = al0; ar = ar0; break;
        case 1: W = W1;  Wt = W1t;  K = 128; M = 128; rows = 144; H = 4; D = 32; al = al1; ar = ar1; break;
        case 2: W = rW1; Wt = rW1t; K = 128; M = 128; rows = 128; H = 0; D = 0;  al = nullptr; ar = nullptr; break;
        case 3: W = W2;  Wt = W2t;  K = 128; M = 47;  rows = 64;  H = 1; D = 47; al = al2; ar = ar2; break;
        default: W = rW2; Wt = rW2t; K = 128; M = 47; rows = 48;  H = 0; D = 0;  al = nullptr; ar = nullptr; break;
    }
    int i = blockIdx.x * 256 + threadIdx.x;
    if (i >= rows * K) return;
    int row = i / K, k = i - row * K;
    float v = 0.f;
    if (row < M) {
        v = W[(long)k * M + row];
    } else if (H > 0 && row < M + 2 * H) {
        int idx = row - M;
        int h = (idx < H) ? idx : idx - H;
        const float* a = (idx < H) ? al : ar;
        float s = 0.f;
        for (int d = 0; d < D; ++d) s += W[(long)k * M + h * D + d] * a[h * D + d];
        v = s;
    }
    Wt[i] = __float2bfloat16(v);
}

// ---- bf16 MFMA GEMM + fused attn projections ----
template <bool A_F32, int NT1, int NT2, int HH>
__global__ __launch_bounds__(256) void gemm_mfma(
    const void* __restrict__ Av, const bf16* __restrict__ B1t,
    const bf16* __restrict__ B2t,
    bf16* __restrict__ C1b, float* __restrict__ el, float* __restrict__ er,
    float* __restrict__ C2, int N, int K, int M) {
    constexpr int LP = 56;  // 32 k + pad: rows 112B (16B-aligned, 2-way alias = free)
    __shared__ bf16 As[64][LP];
    __shared__ bf16 Bs1[NT1 * 16][LP];
    __shared__ bf16 Bs2[(NT2 > 0) ? NT2 * 16 : 1][LP];

    const int tid = threadIdx.x;
    const int lane = tid & 63;
    const int wid = tid >> 6;
    const int row0 = blockIdx.x * 64;
    const int l15 = lane & 15;
    const int kq = lane >> 4;          // k-quarter 0..3

    f32x4 acc1[NT1], acc2[(NT2 > 0) ? NT2 : 1];
    #pragma unroll
    for (int t = 0; t < NT1; ++t) acc1[t] = (f32x4){0.f, 0.f, 0.f, 0.f};
    if constexpr (NT2 > 0) {
        #pragma unroll
        for (int t = 0; t < NT2; ++t) acc2[t] = (f32x4){0.f, 0.f, 0.f, 0.f};
    }

    for (int k0 = 0; k0 < K; k0 += 32) {
        {
            const int r = tid >> 2, kk = (tid & 3) * 8;
            const int gr = row0 + r;
            if constexpr (A_F32) {
                const float* A = (const float*)Av;
                short tmp[8];
                if (gr < N) {
                    const float4 v0 = *(const float4*)&A[(long)gr * K + k0 + kk];
                    const float4 v1 = *(const float4*)&A[(long)gr * K + k0 + kk + 4];
                    tmp[0] = f2bf(v0.x); tmp[1] = f2bf(v0.y); tmp[2] = f2bf(v0.z); tmp[3] = f2bf(v0.w);
                    tmp[4] = f2bf(v1.x); tmp[5] = f2bf(v1.y); tmp[6] = f2bf(v1.z); tmp[7] = f2bf(v1.w);
                } else {
                    #pragma unroll
                    for (int j = 0; j < 8; ++j) tmp[j] = 0;
                }
                *(frag_ab*)&As[r][kk] = *(const frag_ab*)tmp;
            } else {
                const bf16* A = (const bf16*)Av;
                frag_ab v = {0, 0, 0, 0, 0, 0, 0, 0};
                if (gr < N) v = *(const frag_ab*)&A[(long)gr * K + k0 + kk];
                *(frag_ab*)&As[r][kk] = v;
            }
        }
        for (int i = tid; i < NT1 * 64; i += 256) {
            const int c = i >> 2, kk = (i & 3) * 8;
            *(frag_ab*)&Bs1[c][kk] = *(const frag_ab*)&B1t[(long)c * K + k0 + kk];
        }
        if constexpr (NT2 > 0) {
            for (int i = tid; i < NT2 * 64; i += 256) {
                const int c = i >> 2, kk = (i & 3) * 8;
                *(frag_ab*)&Bs2[c][kk] = *(const frag_ab*)&B2t[(long)c * K + k0 + kk];
            }
        }
        __syncthreads();

        const frag_ab a = *(const frag_ab*)&As[wid * 16 + l15][kq * 8];
        #pragma unroll
        for (int t = 0; t < NT1; ++t) {
            const frag_ab b = *(const frag_ab*)&Bs1[t * 16 + l15][kq * 8];
            acc1[t] = __builtin_amdgcn_mfma_f32_16x16x32_bf16(a, b, acc1[t], 0, 0, 0);
        }
        if constexpr (NT2 > 0) {
            #pragma unroll
            for (int t = 0; t < NT2; ++t) {
                const frag_ab b = *(const frag_ab*)&Bs2[t * 16 + l15][kq * 8];
                acc2[t] = __builtin_amdgcn_mfma_f32_16x16x32_bf16(a, b, acc2[t], 0, 0, 0);
            }
        }
        __syncthreads();
    }

    const int r0 = row0 + wid * 16 + kq * 4;
    #pragma unroll
    for (int t = 0; t < NT1; ++t) {
        const int c = t * 16 + l15;
        #pragma unroll
        for (int reg = 0; reg < 4; ++reg) {
            const int r = r0 + reg;
            if (r >= N) continue;
            const float v = acc1[t][reg];
            if (c < M) {
                C1b[(long)r * M + c] = __float2bfloat16(v);
            } else if (c < M + HH) {
                el[(long)r * HH + (c - M)] = v;
            } else if (c < M + 2 * HH) {
                er[(long)r * HH + (c - M - HH)] = v;
            }
        }
    }
    if constexpr (NT2 > 0) {
        #pragma unroll
        for (int t = 0; t < NT2; ++t) {
            const int c = t * 16 + l15;
            if (c >= M) continue;
            #pragma unroll
            for (int reg = 0; reg < 4; ++reg) {
                const int r = r0 + reg;
                if (r < N) C2[(long)r * M + c] = acc2[t][reg];
            }
        }
    }
}

// ---- node softmax + aggregation, one wave/node, H=4 D=32 (HD=128) ----
template <int NELU, bool HAS_RES>
__global__ __launch_bounds__(256) void node_agg4(
    const bf16* __restrict__ featb, const float4* __restrict__ el4,
    const float4* __restrict__ er4, float4* __restrict__ es4,
    const int* __restrict__ offs, const int* __restrict__ srcs,
    const float* __restrict__ res, bf16* __restrict__ out) {
    __shared__ float4 sc[4][64];      // per-wave score cache (4 KB)
    const int node = (int)((blockIdx.x * blockDim.x + threadIdx.x) >> 6);
    const int lane = threadIdx.x & 63;
    const int wid = threadIdx.x >> 6;
    const int beg = offs[node], end = offs[node + 1];
    const float4 ern = er4[node];   // wave-uniform

    // phase A
    float4 s4 = make_float4(0.f, 0.f, 0.f, 0.f);
    for (int i = beg + lane; i < end; i += 64) {
        const float4 elv = el4[srcs[i]];
        float4 t;
        t.x = expw(elv.x + ern.x); t.y = expw(elv.y + ern.y);
        t.z = expw(elv.z + ern.z); t.w = expw(elv.w + ern.w);
        s4.x += t.x; s4.y += t.y; s4.z += t.z; s4.w += t.w;
        const int idx = i - beg;
        if (idx < 64) sc[wid][idx] = t;
        else es4[i] = t;
    }
    #pragma unroll
    for (int off = 32; off > 0; off >>= 1) {
        s4.x += __shfl_xor(s4.x, off);
        s4.y += __shfl_xor(s4.y, off);
        s4.z += __shfl_xor(s4.z, off);
        s4.w += __shfl_xor(s4.w, off);
    }
    __syncthreads();   // orders spill stores + LDS writes before phase-B reads

    // phase B: two edges per iteration (half-wave each)
    const int half = lane >> 5;
    const int l31 = lane & 31;
    const int fi = l31 * 4;           // 4 consecutive features
    const int h = l31 >> 3;           // fi / 32
    const float sh = (h == 0) ? s4.x : (h == 1) ? s4.y : (h == 2) ? s4.z : s4.w;
    const float inv = 1.f / fmaxf(sh, 1e-9f);
    const float* esf = (const float*)es4;
    const float* scf = (const float*)sc[wid];

    float a0 = 0.f, a1 = 0.f, a2 = 0.f, a3 = 0.f;
    int i = beg + half;
    for (; i + 2 < end; i += 4) {
        const int iB = i + 2;
        const int idxA = i - beg, idxB = iB - beg;
        const int snA = srcs[i], snB = srcs[iB];
        const float wA = (idxA < 64) ? scf[idxA * 4 + h] : esf[i * 4 + h];
        const float wB = (idxB < 64) ? scf[idxB * 4 + h] : esf[iB * 4 + h];
        const ushort4 fA = *(const ushort4*)(featb + (long)snA * 128 + fi);
        const ushort4 fB = *(const ushort4*)(featb + (long)snB * 128 + fi);
        a0 += wA * b2f(fA.x) + wB * b2f(fB.x);
        a1 += wA * b2f(fA.y) + wB * b2f(fB.y);
        a2 += wA * b2f(fA.z) + wB * b2f(fB.z);
        a3 += wA * b2f(fA.w) + wB * b2f(fB.w);
    }
    for (; i < end; i += 2) {
        const int idx = i - beg;
        const int sn = srcs[i];
        const float w = (idx < 64) ? scf[idx * 4 + h] : esf[i * 4 + h];
        const ushort4 f = *(const ushort4*)(featb + (long)sn * 128 + fi);
        a0 += w * b2f(f.x); a1 += w * b2f(f.y);
        a2 += w * b2f(f.z); a3 += w * b2f(f.w);
    }
    a0 += __shfl_xor(a0, 32);
    a1 += __shfl_xor(a1, 32);
    a2 += __shfl_xor(a2, 32);
    a3 += __shfl_xor(a3, 32);

    if (lane < 32) {
        float v0 = a0 * inv, v1 = a1 * inv, v2 = a2 * inv, v3 = a3 * inv;
        if constexpr (HAS_RES) {
            const float4 rr = *(const float4*)(res + (long)node * 128 + fi);
            v0 += rr.x; v1 += rr.y; v2 += rr.z; v3 += rr.w;
        }
        #pragma unroll
        for (int t = 0; t < NELU; ++t) {
            v0 = (v0 > 0.f) ? v0 : expm1f(v0);
            v1 = (v1 > 0.f) ? v1 : expm1f(v1);
            v2 = (v2 > 0.f) ? v2 : expm1f(v2);
            v3 = (v3 > 0.f) ? v3 : expm1f(v3);
        }
        ushort4 o;
        o.x = (unsigned short)f2bf(v0); o.y = (unsigned short)f2bf(v1);
        o.z = (unsigned short)f2bf(v2); o.w = (unsigned short)f2bf(v3);
        *(ushort4*)(out + (long)node * 128 + fi) = o;
    }
}

// ---- final fused kernel: node_agg1 (blocks < NODE_BLKS) + all edge-score
// outputs e0/e1/e2 (remaining blocks; reads src/dst once for all 3 layers) ----
__global__ __launch_bounds__(256) void final_k(
    const bf16* __restrict__ featb, const float* __restrict__ el2s,
    const float* __restrict__ er2s, float* __restrict__ es1,
    const int* __restrict__ offs, const int* __restrict__ srcs,
    const float* __restrict__ res, float* __restrict__ logits,
    const float4* __restrict__ el0, const float4* __restrict__ er0,
    const float4* __restrict__ el1, const float4* __restrict__ er1,
    const int* __restrict__ src, const int* __restrict__ dst,
    float* __restrict__ e0, float* __restrict__ e1, float* __restrict__ e2) {
    __shared__ float sc1[4][64];      // per-wave score cache (1 KB)
    if (blockIdx.x < NODE_BLKS) {
        const int node = (int)((blockIdx.x * blockDim.x + threadIdx.x) >> 6);
        const int lane = threadIdx.x & 63;
        const int wid = threadIdx.x >> 6;
        const int beg = offs[node], end = offs[node + 1];
        const float ern = er2s[node];

        float s = 0.f;
        for (int i = beg + lane; i < end; i += 64) {
            const float t = expw(el2s[srcs[i]] + ern);
            s += t;
            const int idx = i - beg;
            if (idx < 64) sc1[wid][idx] = t;
            else es1[i] = t;
        }
        #pragma unroll
        for (int off = 32; off > 0; off >>= 1) s += __shfl_xor(s, off);
        const float inv = 1.f / fmaxf(s, 1e-9f);
        __syncthreads();

        // aggregation with explicit 4-deep unroll (4 gathers in flight)
        const bool active = lane < NC;
        float acc = 0.f;
        int i = beg;
        for (; i + 4 <= end; i += 4) {
            const int d0 = i - beg;
            const int sn0 = srcs[i], sn1 = srcs[i + 1], sn2 = srcs[i + 2], sn3 = srcs[i + 3];
            const float w0 = (d0 + 0 < 64) ? sc1[wid][d0 + 0] : es1[i + 0];
            const float w1 = (d0 + 1 < 64) ? sc1[wid][d0 + 1] : es1[i + 1];
            const float w2 = (d0 + 2 < 64) ? sc1[wid][d0 + 2] : es1[i + 2];
            const float w3 = (d0 + 3 < 64) ? sc1[wid][d0 + 3] : es1[i + 3];
            if (active) {
                acc += w0 * __bfloat162float(featb[(long)sn0 * NC + lane]);
                acc += w1 * __bfloat162float(featb[(long)sn1 * NC + lane]);
                acc += w2 * __bfloat162float(featb[(long)sn2 * NC + lane]);
                acc += w3 * __bfloat162float(featb[(long)sn3 * NC + lane]);
            }
        }
        for (; i < end; ++i) {
            const int idx = i - beg;
            const float w = (idx < 64) ? sc1[wid][idx] : es1[i];
            if (active) acc += w * __bfloat162float(featb[(long)srcs[i] * NC + lane]);
        }
        if (active) {
            logits[(long)node * NC + lane] = acc * inv + res[(long)node * NC + lane];
        }
    } else {
        const int e = (blockIdx.x - NODE_BLKS) * 256 + threadIdx.x;  // exact NE
        const int s = src[e], d = dst[e];
        const float4 a0 = el0[s], b0 = er0[d];
        float4 v0;
        v0.x = lrelu(a0.x + b0.x); v0.y = lrelu(a0.y + b0.y);
        v0.z = lrelu(a0.z + b0.z); v0.w = lrelu(a0.w + b0.w);
        *reinterpret_cast<float4*>(e0 + e * 4) = v0;
        const float4 a1 = el1[s], b1 = er1[d];
        float4 v1;
        v1.x = lrelu(a1.x + b1.x); v1.y = lrelu(a1.y + b1.y);
        v1.z = lrelu(a1.z + b1.z); v1.w = lrelu(a1.w + b1.w);
        *reinterpret_cast<float4*>(e1 + e * 4) = v1;
        e2[e] = lrelu(el2s[s] + er2s[d]);
    }
}

extern "C" void kernel_launch(void* const* d_in, const int* in_sizes, int n_in,
                              void* d_out, int out_size, void* d_ws, size_t ws_size,
                              hipStream_t stream) {
    const float* x     = (const float*)d_in[0];
    const float* W0    = (const float*)d_in[1];
    const float* al0   = (const float*)d_in[2];
    const float* ar0   = (const float*)d_in[3];
    const float* W1    = (const float*)d_in[4];
    const float* resW1 = (const float*)d_in[5];
    const float* al1   = (const float*)d_in[6];
    const float* ar1   = (const float*)d_in[7];
    const float* W2    = (const float*)d_in[8];
    const float* resW2 = (const float*)d_in[9];
    const float* al2   = (const float*)d_in[10];
    const float* ar2   = (const float*)d_in[11];
    const int*   src   = (const int*)d_in[12];
    const int*   dst   = (const int*)d_in[13];

    float* out    = (float*)d_out;
    float* logits = out;                 // [N, 47]
    float* e0     = out + (long)NN * NC; // [E, 4]
    float* e1     = e0 + (long)NE * NH;  // [E, 4]
    float* e2     = e1 + (long)NE * NH;  // [E, 1]

    char* p = (char*)d_ws;
    int* offs   = (int*)p; p += align256(sizeof(int) * (NN + 1));
    int* cursor = (int*)p; p += align256(sizeof(int) * NN);
    int* srcs   = (int*)p; p += align256(sizeof(int) * NE);
    float* el0b = (float*)p; p += align256(sizeof(float) * NN * NH);
    float* er0b = (float*)p; p += align256(sizeof(float) * NN * NH);
    float* el1b = (float*)p; p += align256(sizeof(float) * NN * NH);
    float* er1b = (float*)p; p += align256(sizeof(float) * NN * NH);
    float* el2b = (float*)p; p += align256(sizeof(float) * NN);
    float* er2b = (float*)p; p += align256(sizeof(float) * NN);
    float* es   = (float*)p; p += align256(sizeof(float) * (long)NE * NH);  // spill fallback
    float* resb = (float*)p; p += align256(sizeof(float) * (long)NN * 128);
    bf16* featb = (bf16*)p; p += align256(sizeof(bf16) * (long)NN * 128);
    bf16* hb    = (bf16*)p; p += align256(sizeof(bf16) * (long)NN * 128);
    bf16* W0t   = (bf16*)p; p += align256(sizeof(bf16) * 144 * 256);
    bf16* W1t   = (bf16*)p; p += align256(sizeof(bf16) * 144 * 128);
    bf16* rW1t  = (bf16*)p; p += align256(sizeof(bf16) * 128 * 128);
    bf16* W2t   = (bf16*)p; p += align256(sizeof(bf16) * 64 * 128);
    bf16* rW2t  = (bf16*)p; p += align256(sizeof(bf16) * 48 * 128);

    // ---- weight prep + cursor zero (y==5) ----
    prep_w_all<<<dim3(144, 6), 256, 0, stream>>>(W0, W1, resW1, W2, resW2,
                                                 al0, ar0, al1, ar1, al2, ar2,
                                                 W0t, W1t, rW1t, W2t, rW2t, cursor);

    // ---- CSR by dst ----
    count_k<<<EDGE_BLKS, 256, 0, stream>>>(dst, cursor, NE);
    scan_k<<<1, 1024, 0, stream>>>(cursor, offs, cursor, NN);
    fill_k<<<EDGE_BLKS, 256, 0, stream>>>(dst, src, cursor, srcs, NE);

    const int gemmBlocks = (NN + 63) / 64;   // 469

    // ---- layer 0: x @ [W0|wl0|wr0] -> featb bf16 + el0 + er0 ----
    gemm_mfma<true, 9, 0, NH><<<gemmBlocks, 256, 0, stream>>>(
        x, W0t, nullptr, featb, el0b, er0b, nullptr, NN, FIN, 128);
    node_agg4<1, false><<<NODE_BLKS, 256, 0, stream>>>(
        featb, (const float4*)el0b, (const float4*)er0b, (float4*)es, offs, srcs, nullptr, hb);

    // ---- layer 1: hb @ [W1|wl1|wr1] + hb @ resW1 -> featb/el1/er1 + resb ----
    gemm_mfma<false, 9, 8, NH><<<gemmBlocks, 256, 0, stream>>>(
        hb, W1t, rW1t, featb, el1b, er1b, resb, NN, 128, 128);
    node_agg4<2, true><<<NODE_BLKS, 256, 0, stream>>>(
        featb, (const float4*)el1b, (const float4*)er1b, (float4*)es, offs, srcs, resb, hb);

    // ---- final layer: hb @ [W2|wl2|wr2] + hb @ resW2 (M=47) ----
    gemm_mfma<false, 4, 3, 1><<<gemmBlocks, 256, 0, stream>>>(
        hb, W2t, rW2t, featb, el2b, er2b, resb, NN, 128, NC);
    // fused: node_agg1 (logits) + e0/e1/e2 edge-score outputs
    final_k<<<NODE_BLKS + EDGE_BLKS, 256, 0, stream>>>(
        featb, el2b, er2b, es, offs, srcs, resb, logits,
        (const float4*)el0b, (const float4*)er0b,
        (const float4*)el1b, (const float4*)er1b,
        src, dst, e0, e1, e2);
}

// Round 11
// 203.928 us; speedup vs baseline: 1.2435x; 1.1244x over previous
//
#include <hip/hip_runtime.h>
#include <hip/hip_bf16.h>
#include <math.h>

// Problem constants
#define NN 30000
#define NE 480000
#define FIN 256
#define DH 32
#define NH 4
#define NC 47
#define NODE_BLKS 7500   // NN/4 (4 waves/block, 1 wave/node)
#define EDGE_BLKS 1875   // NE/256
#define SCAN_CHUNK 1000  // 30 chunks of 1000

typedef __attribute__((ext_vector_type(8))) short frag_ab;  // 8 bf16 (4 VGPR)
typedef __attribute__((ext_vector_type(4))) float f32x4;    // MFMA 16x16 accum
typedef __hip_bfloat16 bf16;

static inline size_t align256(size_t x) { return (x + 255) & ~(size_t)255; }

__device__ __forceinline__ short f2bf(float f) {
    union { float f; unsigned u; } c; c.f = f;
    unsigned r = (c.u + 0x7FFFu + ((c.u >> 16) & 1u)) >> 16;  // RNE
    return (short)r;
}
__device__ __forceinline__ float b2f(unsigned short u) {
    union { unsigned u; float f; } c; c.u = (unsigned)u << 16; return c.f;
}
// exp(leaky_relu(v)) — no max subtraction (scores O(10), far from f32 overflow)
__device__ __forceinline__ float expw(float v) {
    return __expf((v >= 0.f) ? v : 0.2f * v);
}
__device__ __forceinline__ float lrelu(float v) {
    return (v >= 0.f) ? v : 0.2f * v;
}

// ---------------- CSR build ----------------
__global__ void count_k(const int* __restrict__ dst, int* __restrict__ cnt, int E) {
    int e = blockIdx.x * blockDim.x + threadIdx.x;
    if (e < E) atomicAdd(&cnt[dst[e]], 1);
}

// multi-block scan, stage A: per-chunk local exclusive scan + chunk sum
__global__ __launch_bounds__(1024) void scanA(const int* __restrict__ cnt,
                                              int* __restrict__ offs,
                                              int* __restrict__ bsum) {
    __shared__ int warp_sums[16];
    const int lane = threadIdx.x & 63;
    const int wid = threadIdx.x >> 6;
    const int g = blockIdx.x * SCAN_CHUNK + threadIdx.x;
    const bool valid = (threadIdx.x < SCAN_CHUNK) && (g < NN);
    int v = valid ? cnt[g] : 0;
    int x = v;
    #pragma unroll
    for (int off = 1; off < 64; off <<= 1) {
        int y = __shfl_up(x, off);
        if (lane >= off) x += y;
    }
    if (lane == 63) warp_sums[wid] = x;
    __syncthreads();
    if (wid == 0) {
        int ws = (lane < 16) ? warp_sums[lane] : 0;
        #pragma unroll
        for (int off = 1; off < 16; off <<= 1) {
            int y = __shfl_up(ws, off);
            if (lane >= off) ws += y;
        }
        if (lane < 16) warp_sums[lane] = ws;
    }
    __syncthreads();
    const int wbase = (wid > 0) ? warp_sums[wid - 1] : 0;
    const int incl = x + wbase;
    if (valid) offs[g] = incl - v;                  // chunk-local exclusive
    if (threadIdx.x == 1023) bsum[blockIdx.x] = incl;  // chunk total
}

// stage B: add scanned chunk bases; write offs (global) + cursor; offs[NN]=total
__global__ __launch_bounds__(256) void scanB(const int* __restrict__ bsum,
                                             int* __restrict__ offs,
                                             int* __restrict__ cursor) {
    __shared__ int bases[31];
    if (threadIdx.x == 0) {
        int acc = 0;
        for (int j = 0; j < 30; ++j) { bases[j] = acc; acc += bsum[j]; }
        bases[30] = acc;
    }
    __syncthreads();
    const int i = blockIdx.x * 256 + threadIdx.x;
    if (i < NN) {
        const int o = offs[i] + bases[i / SCAN_CHUNK];
        offs[i] = o;
        cursor[i] = o;
    }
    if (i == 0) offs[NN] = bases[30];
}

// srcs[slot] = src id, in CSR-by-dst order
__global__ void fill_k(const int* __restrict__ dst, const int* __restrict__ src,
                       int* __restrict__ cursor, int* __restrict__ srcs, int E) {
    int e = blockIdx.x * blockDim.x + threadIdx.x;
    if (e < E) {
        int p = atomicAdd(&cursor[dst[e]], 1);
        srcs[p] = src[e];
    }
}

// ---- weight prep (+ cursor zeroing in y==5): transposed bf16 weights with
// fused el/er projection rows. Rows 0..M-1 = W^T; M..M+H-1 = W·al; M+H..M+2H-1 = W·ar.
__global__ void prep_w_all(const float* __restrict__ W0, const float* __restrict__ W1,
                           const float* __restrict__ rW1, const float* __restrict__ W2,
                           const float* __restrict__ rW2,
                           const float* __restrict__ al0, const float* __restrict__ ar0,
                           const float* __restrict__ al1, const float* __restrict__ ar1,
                           const float* __restrict__ al2, const float* __restrict__ ar2,
                           bf16* __restrict__ W0t, bf16* __restrict__ W1t,
                           bf16* __restrict__ rW1t, bf16* __restrict__ W2t,
                           bf16* __restrict__ rW2t, int* __restrict__ cursor) {
    if (blockIdx.y == 5) {
        int i = blockIdx.x * 256 + threadIdx.x;
        if (i < NN) cursor[i] = 0;
        return;
    }
    const float *W, *al, *ar; bf16* Wt; int K, M, rows, H, D;
    switch (blockIdx.y) {
        case 0: W = W0;  Wt = W0t;  K = 256; M = 128; rows = 144; H = 4; D = 32; al = al0; ar = ar0; break;
        case 1: W = W1;  Wt = W1t;  K = 128; M = 128; rows = 144; H = 4; D = 32; al = al1; ar = ar1; break;
        case 2: W = rW1; Wt = rW1t; K = 128; M = 128; rows = 128; H = 0; D = 0;  al = nullptr; ar = nullptr; break;
        case 3: W = W2;  Wt = W2t;  K = 128; M = 47;  rows = 64;  H = 1; D = 47; al = al2; ar = ar2; break;
        default: W = rW2; Wt = rW2t; K = 128; M = 47; rows = 48;  H = 0; D = 0;  al = nullptr; ar = nullptr; break;
    }
    int i = blockIdx.x * 256 + threadIdx.x;
    if (i >= rows * K) return;
    int row = i / K, k = i - row * K;
    float v = 0.f;
    if (row < M) {
        v = W[(long)k * M + row];
    } else if (H > 0 && row < M + 2 * H) {
        int idx = row - M;
        int h = (idx < H) ? idx : idx - H;
        const float* a = (idx < H) ? al : ar;
        float s = 0.f;
        for (int d = 0; d < D; ++d) s += W[(long)k * M + h * D + d] * a[h * D + d];
        v = s;
    }
    Wt[i] = __float2bfloat16(v);
}

// ---- bf16 MFMA GEMM + fused attn projections ----
template <bool A_F32, int NT1, int NT2, int HH>
__global__ __launch_bounds__(256) void gemm_mfma(
    const void* __restrict__ Av, const bf16* __restrict__ B1t,
    const bf16* __restrict__ B2t,
    bf16* __restrict__ C1b, float* __restrict__ el, float* __restrict__ er,
    float* __restrict__ C2, int N, int K, int M) {
    constexpr int LP = 56;  // 32 k + pad: rows 112B (16B-aligned, 2-way alias = free)
    __shared__ bf16 As[64][LP];
    __shared__ bf16 Bs1[NT1 * 16][LP];
    __shared__ bf16 Bs2[(NT2 > 0) ? NT2 * 16 : 1][LP];

    const int tid = threadIdx.x;
    const int lane = tid & 63;
    const int wid = tid >> 6;
    const int row0 = blockIdx.x * 64;
    const int l15 = lane & 15;
    const int kq = lane >> 4;          // k-quarter 0..3

    f32x4 acc1[NT1], acc2[(NT2 > 0) ? NT2 : 1];
    #pragma unroll
    for (int t = 0; t < NT1; ++t) acc1[t] = (f32x4){0.f, 0.f, 0.f, 0.f};
    if constexpr (NT2 > 0) {
        #pragma unroll
        for (int t = 0; t < NT2; ++t) acc2[t] = (f32x4){0.f, 0.f, 0.f, 0.f};
    }

    for (int k0 = 0; k0 < K; k0 += 32) {
        {
            const int r = tid >> 2, kk = (tid & 3) * 8;
            const int gr = row0 + r;
            if constexpr (A_F32) {
                const float* A = (const float*)Av;
                short tmp[8];
                if (gr < N) {
                    const float4 v0 = *(const float4*)&A[(long)gr * K + k0 + kk];
                    const float4 v1 = *(const float4*)&A[(long)gr * K + k0 + kk + 4];
                    tmp[0] = f2bf(v0.x); tmp[1] = f2bf(v0.y); tmp[2] = f2bf(v0.z); tmp[3] = f2bf(v0.w);
                    tmp[4] = f2bf(v1.x); tmp[5] = f2bf(v1.y); tmp[6] = f2bf(v1.z); tmp[7] = f2bf(v1.w);
                } else {
                    #pragma unroll
                    for (int j = 0; j < 8; ++j) tmp[j] = 0;
                }
                *(frag_ab*)&As[r][kk] = *(const frag_ab*)tmp;
            } else {
                const bf16* A = (const bf16*)Av;
                frag_ab v = {0, 0, 0, 0, 0, 0, 0, 0};
                if (gr < N) v = *(const frag_ab*)&A[(long)gr * K + k0 + kk];
                *(frag_ab*)&As[r][kk] = v;
            }
        }
        for (int i = tid; i < NT1 * 64; i += 256) {
            const int c = i >> 2, kk = (i & 3) * 8;
            *(frag_ab*)&Bs1[c][kk] = *(const frag_ab*)&B1t[(long)c * K + k0 + kk];
        }
        if constexpr (NT2 > 0) {
            for (int i = tid; i < NT2 * 64; i += 256) {
                const int c = i >> 2, kk = (i & 3) * 8;
                *(frag_ab*)&Bs2[c][kk] = *(const frag_ab*)&B2t[(long)c * K + k0 + kk];
            }
        }
        __syncthreads();

        const frag_ab a = *(const frag_ab*)&As[wid * 16 + l15][kq * 8];
        #pragma unroll
        for (int t = 0; t < NT1; ++t) {
            const frag_ab b = *(const frag_ab*)&Bs1[t * 16 + l15][kq * 8];
            acc1[t] = __builtin_amdgcn_mfma_f32_16x16x32_bf16(a, b, acc1[t], 0, 0, 0);
        }
        if constexpr (NT2 > 0) {
            #pragma unroll
            for (int t = 0; t < NT2; ++t) {
                const frag_ab b = *(const frag_ab*)&Bs2[t * 16 + l15][kq * 8];
                acc2[t] = __builtin_amdgcn_mfma_f32_16x16x32_bf16(a, b, acc2[t], 0, 0, 0);
            }
        }
        __syncthreads();
    }

    const int r0 = row0 + wid * 16 + kq * 4;
    #pragma unroll
    for (int t = 0; t < NT1; ++t) {
        const int c = t * 16 + l15;
        #pragma unroll
        for (int reg = 0; reg < 4; ++reg) {
            const int r = r0 + reg;
            if (r >= N) continue;
            const float v = acc1[t][reg];
            if (c < M) {
                C1b[(long)r * M + c] = __float2bfloat16(v);
            } else if (c < M + HH) {
                el[(long)r * HH + (c - M)] = v;
            } else if (c < M + 2 * HH) {
                er[(long)r * HH + (c - M - HH)] = v;
            }
        }
    }
    if constexpr (NT2 > 0) {
        #pragma unroll
        for (int t = 0; t < NT2; ++t) {
            const int c = t * 16 + l15;
            if (c >= M) continue;
            #pragma unroll
            for (int reg = 0; reg < 4; ++reg) {
                const int r = r0 + reg;
                if (r < N) C2[(long)r * M + c] = acc2[t][reg];
            }
        }
    }
}

// ---- node softmax + aggregation, one wave/node, H=4 D=32 (HD=128) ----
// Phase A (lane-strided): t = exp(lrelu(el[src]+er[node])), s += t;
//   first 64 edges cached in LDS; rest spill to global es (never in practice).
// Phase B (quarter-wave per edge): 16 lanes x ushort8 (16B) cover the full
//   256B feat row; 4 quarters x 2-deep unroll = 8 gathers in flight.
template <int NELU, bool HAS_RES>
__global__ __launch_bounds__(256) void node_agg4(
    const bf16* __restrict__ featb, const float4* __restrict__ el4,
    const float4* __restrict__ er4, float4* __restrict__ es4,
    const int* __restrict__ offs, const int* __restrict__ srcs,
    const float* __restrict__ res, bf16* __restrict__ out) {
    __shared__ float4 sc[4][64];      // per-wave score cache (4 KB/wave)
    const int node = (int)((blockIdx.x * blockDim.x + threadIdx.x) >> 6);
    const int lane = threadIdx.x & 63;
    const int wid = threadIdx.x >> 6;
    const int beg = offs[node], end = offs[node + 1];
    const float4 ern = er4[node];   // wave-uniform

    // phase A
    float4 s4 = make_float4(0.f, 0.f, 0.f, 0.f);
    for (int i = beg + lane; i < end; i += 64) {
        const float4 elv = el4[srcs[i]];
        float4 t;
        t.x = expw(elv.x + ern.x); t.y = expw(elv.y + ern.y);
        t.z = expw(elv.z + ern.z); t.w = expw(elv.w + ern.w);
        s4.x += t.x; s4.y += t.y; s4.z += t.z; s4.w += t.w;
        const int idx = i - beg;
        if (idx < 64) sc[wid][idx] = t;
        else es4[i] = t;
    }
    #pragma unroll
    for (int off = 32; off > 0; off >>= 1) {
        s4.x += __shfl_xor(s4.x, off);
        s4.y += __shfl_xor(s4.y, off);
        s4.z += __shfl_xor(s4.z, off);
        s4.w += __shfl_xor(s4.w, off);
    }
    __syncthreads();   // orders spill stores + LDS writes before phase-B reads

    // phase B: quarter-wave per edge, ushort8 per lane
    const int q = lane >> 4;          // quarter 0..3
    const int l15 = lane & 15;
    const int fi = l15 * 8;           // 8 consecutive features (same head: 8|32)
    const int h = l15 >> 2;           // fi / 32
    const float sh = (h == 0) ? s4.x : (h == 1) ? s4.y : (h == 2) ? s4.z : s4.w;
    const float inv = 1.f / fmaxf(sh, 1e-9f);
    const float* esf = (const float*)es4;
    const float* scf = (const float*)sc[wid];

    float a[8] = {0.f, 0.f, 0.f, 0.f, 0.f, 0.f, 0.f, 0.f};
    int i = beg + q;
    for (; i + 4 < end; i += 8) {
        const int iB = i + 4;
        const int idxA = i - beg, idxB = iB - beg;
        const int snA = srcs[i], snB = srcs[iB];
        const float wA = (idxA < 64) ? scf[idxA * 4 + h] : esf[i * 4 + h];
        const float wB = (idxB < 64) ? scf[idxB * 4 + h] : esf[iB * 4 + h];
        const frag_ab fA = *(const frag_ab*)(featb + (long)snA * 128 + fi);
        const frag_ab fB = *(const frag_ab*)(featb + (long)snB * 128 + fi);
        #pragma unroll
        for (int j = 0; j < 8; ++j)
            a[j] += wA * b2f((unsigned short)fA[j]) + wB * b2f((unsigned short)fB[j]);
    }
    for (; i < end; i += 4) {
        const int idx = i - beg;
        const int sn = srcs[i];
        const float w = (idx < 64) ? scf[idx * 4 + h] : esf[i * 4 + h];
        const frag_ab f = *(const frag_ab*)(featb + (long)sn * 128 + fi);
        #pragma unroll
        for (int j = 0; j < 8; ++j) a[j] += w * b2f((unsigned short)f[j]);
    }
    #pragma unroll
    for (int j = 0; j < 8; ++j) {
        a[j] += __shfl_xor(a[j], 16);
        a[j] += __shfl_xor(a[j], 32);
    }

    if (lane < 16) {
        float v[8];
        #pragma unroll
        for (int j = 0; j < 8; ++j) v[j] = a[j] * inv;
        if constexpr (HAS_RES) {
            const float4 r0 = *(const float4*)(res + (long)node * 128 + fi);
            const float4 r1 = *(const float4*)(res + (long)node * 128 + fi + 4);
            v[0] += r0.x; v[1] += r0.y; v[2] += r0.z; v[3] += r0.w;
            v[4] += r1.x; v[5] += r1.y; v[6] += r1.z; v[7] += r1.w;
        }
        #pragma unroll
        for (int t = 0; t < NELU; ++t)
            #pragma unroll
            for (int j = 0; j < 8; ++j)
                v[j] = (v[j] > 0.f) ? v[j] : expm1f(v[j]);
        frag_ab o;
        #pragma unroll
        for (int j = 0; j < 8; ++j) o[j] = f2bf(v[j]);
        *(frag_ab*)(out + (long)node * 128 + fi) = o;
    }
}

// ---- final fused kernel: node_agg1 (blocks < NODE_BLKS) + all edge-score
// outputs e0/e1/e2 (remaining blocks; reads src/dst once for all 3 layers) ----
__global__ __launch_bounds__(256) void final_k(
    const bf16* __restrict__ featb, const float* __restrict__ el2s,
    const float* __restrict__ er2s, float* __restrict__ es1,
    const int* __restrict__ offs, const int* __restrict__ srcs,
    const float* __restrict__ res, float* __restrict__ logits,
    const float4* __restrict__ el0, const float4* __restrict__ er0,
    const float4* __restrict__ el1, const float4* __restrict__ er1,
    const int* __restrict__ src, const int* __restrict__ dst,
    float* __restrict__ e0, float* __restrict__ e1, float* __restrict__ e2) {
    __shared__ float sc1[4][64];      // per-wave score cache (1 KB)
    if (blockIdx.x < NODE_BLKS) {
        const int node = (int)((blockIdx.x * blockDim.x + threadIdx.x) >> 6);
        const int lane = threadIdx.x & 63;
        const int wid = threadIdx.x >> 6;
        const int beg = offs[node], end = offs[node + 1];
        const float ern = er2s[node];

        float s = 0.f;
        for (int i = beg + lane; i < end; i += 64) {
            const float t = expw(el2s[srcs[i]] + ern);
            s += t;
            const int idx = i - beg;
            if (idx < 64) sc1[wid][idx] = t;
            else es1[i] = t;
        }
        #pragma unroll
        for (int off = 32; off > 0; off >>= 1) s += __shfl_xor(s, off);
        const float inv = 1.f / fmaxf(s, 1e-9f);
        __syncthreads();

        // aggregation with 8-deep unroll (8 gathers in flight)
        const bool active = lane < NC;
        float acc = 0.f;
        int i = beg;
        for (; i + 8 <= end; i += 8) {
            const int d0 = i - beg;
            int sn[8]; float w[8];
            #pragma unroll
            for (int k = 0; k < 8; ++k) {
                sn[k] = srcs[i + k];
                w[k] = (d0 + k < 64) ? sc1[wid][d0 + k] : es1[i + k];
            }
            if (active) {
                #pragma unroll
                for (int k = 0; k < 8; ++k)
                    acc += w[k] * __bfloat162float(featb[(long)sn[k] * NC + lane]);
            }
        }
        for (; i < end; ++i) {
            const int idx = i - beg;
            const float w = (idx < 64) ? sc1[wid][idx] : es1[i];
            if (active) acc += w * __bfloat162float(featb[(long)srcs[i] * NC + lane]);
        }
        if (active) {
            logits[(long)node * NC + lane] = acc * inv + res[(long)node * NC + lane];
        }
    } else {
        const int e = (blockIdx.x - NODE_BLKS) * 256 + threadIdx.x;  // exact NE
        const int s = src[e], d = dst[e];
        const float4 a0 = el0[s], b0 = er0[d];
        float4 v0;
        v0.x = lrelu(a0.x + b0.x); v0.y = lrelu(a0.y + b0.y);
        v0.z = lrelu(a0.z + b0.z); v0.w = lrelu(a0.w + b0.w);
        *reinterpret_cast<float4*>(e0 + e * 4) = v0;
        const float4 a1 = el1[s], b1 = er1[d];
        float4 v1;
        v1.x = lrelu(a1.x + b1.x); v1.y = lrelu(a1.y + b1.y);
        v1.z = lrelu(a1.z + b1.z); v1.w = lrelu(a1.w + b1.w);
        *reinterpret_cast<float4*>(e1 + e * 4) = v1;
        e2[e] = lrelu(el2s[s] + er2s[d]);
    }
}

extern "C" void kernel_launch(void* const* d_in, const int* in_sizes, int n_in,
                              void* d_out, int out_size, void* d_ws, size_t ws_size,
                              hipStream_t stream) {
    const float* x     = (const float*)d_in[0];
    const float* W0    = (const float*)d_in[1];
    const float* al0   = (const float*)d_in[2];
    const float* ar0   = (const float*)d_in[3];
    const float* W1    = (const float*)d_in[4];
    const float* resW1 = (const float*)d_in[5];
    const float* al1   = (const float*)d_in[6];
    const float* ar1   = (const float*)d_in[7];
    const float* W2    = (const float*)d_in[8];
    const float* resW2 = (const float*)d_in[9];
    const float* al2   = (const float*)d_in[10];
    const float* ar2   = (const float*)d_in[11];
    const int*   src   = (const int*)d_in[12];
    const int*   dst   = (const int*)d_in[13];

    float* out    = (float*)d_out;
    float* logits = out;                 // [N, 47]
    float* e0     = out + (long)NN * NC; // [E, 4]
    float* e1     = e0 + (long)NE * NH;  // [E, 4]
    float* e2     = e1 + (long)NE * NH;  // [E, 1]

    char* p = (char*)d_ws;
    int* offs   = (int*)p; p += align256(sizeof(int) * (NN + 1));
    int* cursor = (int*)p; p += align256(sizeof(int) * NN);
    int* bsum   = (int*)p; p += align256(sizeof(int) * 32);
    int* srcs   = (int*)p; p += align256(sizeof(int) * NE);
    float* el0b = (float*)p; p += align256(sizeof(float) * NN * NH);
    float* er0b = (float*)p; p += align256(sizeof(float) * NN * NH);
    float* el1b = (float*)p; p += align256(sizeof(float) * NN * NH);
    float* er1b = (float*)p; p += align256(sizeof(float) * NN * NH);
    float* el2b = (float*)p; p += align256(sizeof(float) * NN);
    float* er2b = (float*)p; p += align256(sizeof(float) * NN);
    float* es   = (float*)p; p += align256(sizeof(float) * (long)NE * NH);  // spill fallback
    float* resb = (float*)p; p += align256(sizeof(float) * (long)NN * 128);
    bf16* featb = (bf16*)p; p += align256(sizeof(bf16) * (long)NN * 128);
    bf16* hb    = (bf16*)p; p += align256(sizeof(bf16) * (long)NN * 128);
    bf16* W0t   = (bf16*)p; p += align256(sizeof(bf16) * 144 * 256);
    bf16* W1t   = (bf16*)p; p += align256(sizeof(bf16) * 144 * 128);
    bf16* rW1t  = (bf16*)p; p += align256(sizeof(bf16) * 128 * 128);
    bf16* W2t   = (bf16*)p; p += align256(sizeof(bf16) * 64 * 128);
    bf16* rW2t  = (bf16*)p; p += align256(sizeof(bf16) * 48 * 128);

    // ---- weight prep + cursor zero (y==5) ----
    prep_w_all<<<dim3(144, 6), 256, 0, stream>>>(W0, W1, resW1, W2, resW2,
                                                 al0, ar0, al1, ar1, al2, ar2,
                                                 W0t, W1t, rW1t, W2t, rW2t, cursor);

    // ---- CSR by dst (multi-block scan) ----
    count_k<<<EDGE_BLKS, 256, 0, stream>>>(dst, cursor, NE);
    scanA<<<30, 1024, 0, stream>>>(cursor, offs, bsum);
    scanB<<<(NN + 255) / 256, 256, 0, stream>>>(bsum, offs, cursor);
    fill_k<<<EDGE_BLKS, 256, 0, stream>>>(dst, src, cursor, srcs, NE);

    const int gemmBlocks = (NN + 63) / 64;   // 469

    // ---- layer 0: x @ [W0|wl0|wr0] -> featb bf16 + el0 + er0 ----
    gemm_mfma<true, 9, 0, NH><<<gemmBlocks, 256, 0, stream>>>(
        x, W0t, nullptr, featb, el0b, er0b, nullptr, NN, FIN, 128);
    node_agg4<1, false><<<NODE_BLKS, 256, 0, stream>>>(
        featb, (const float4*)el0b, (const float4*)er0b, (float4*)es, offs, srcs, nullptr, hb);

    // ---- layer 1: hb @ [W1|wl1|wr1] + hb @ resW1 -> featb/el1/er1 + resb ----
    gemm_mfma<false, 9, 8, NH><<<gemmBlocks, 256, 0, stream>>>(
        hb, W1t, rW1t, featb, el1b, er1b, resb, NN, 128, 128);
    node_agg4<2, true><<<NODE_BLKS, 256, 0, stream>>>(
        featb, (const float4*)el1b, (const float4*)er1b, (float4*)es, offs, srcs, resb, hb);

    // ---- final layer: hb @ [W2|wl2|wr2] + hb @ resW2 (M=47) ----
    gemm_mfma<false, 4, 3, 1><<<gemmBlocks, 256, 0, stream>>>(
        hb, W2t, rW2t, featb, el2b, er2b, resb, NN, 128, NC);
    // fused: node_agg1 (logits) + e0/e1/e2 edge-score outputs
    final_k<<<NODE_BLKS + EDGE_BLKS, 256, 0, stream>>>(
        featb, el2b, er2b, es, offs, srcs, resb, logits,
        (const float4*)el0b, (const float4*)er0b,
        (const float4*)el1b, (const float4*)er1b,
        src, dst, e0, e1, e2);
}

// Round 12
// 201.662 us; speedup vs baseline: 1.2575x; 1.0112x over previous
//
#include <hip/hip_runtime.h>
#include <hip/hip_bf16.h>
#include <math.h>

// Problem constants
#define NN 30000
#define NE 480000
#define FIN 256
#define DH 32
#define NH 4
#define NC 47
#define NODE_BLKS 7500   // NN/4 (4 waves/block, 1 wave/node)
#define EDGE_BLKS 1875   // NE/256
#define SCAN_CHUNK 1024  // 30 chunks of 1024 (30720 >= 30000)
#define NCHUNKS 30

typedef __attribute__((ext_vector_type(8))) short frag_ab;  // 8 bf16 (4 VGPR)
typedef __attribute__((ext_vector_type(4))) float f32x4;    // MFMA 16x16 accum
typedef __hip_bfloat16 bf16;

static inline size_t align256(size_t x) { return (x + 255) & ~(size_t)255; }

__device__ __forceinline__ short f2bf(float f) {
    union { float f; unsigned u; } c; c.f = f;
    unsigned r = (c.u + 0x7FFFu + ((c.u >> 16) & 1u)) >> 16;  // RNE
    return (short)r;
}
__device__ __forceinline__ float b2f(unsigned short u) {
    union { unsigned u; float f; } c; c.u = (unsigned)u << 16; return c.f;
}
// exp(leaky_relu(v)) — no max subtraction (scores O(10), far from f32 overflow)
__device__ __forceinline__ float expw(float v) {
    return __expf((v >= 0.f) ? v : 0.2f * v);
}
__device__ __forceinline__ float lrelu(float v) {
    return (v >= 0.f) ? v : 0.2f * v;
}

// ---- weight prep (y<5) ∥ CSR count (y==5). cursor must be zeroed beforehand
// (hipMemsetAsync). Transposed bf16 weights with fused el/er projection rows:
// rows 0..M-1 = W^T; M..M+H-1 = W·al; M+H..M+2H-1 = W·ar.
__global__ void prep_count(const float* __restrict__ W0, const float* __restrict__ W1,
                           const float* __restrict__ rW1, const float* __restrict__ W2,
                           const float* __restrict__ rW2,
                           const float* __restrict__ al0, const float* __restrict__ ar0,
                           const float* __restrict__ al1, const float* __restrict__ ar1,
                           const float* __restrict__ al2, const float* __restrict__ ar2,
                           bf16* __restrict__ W0t, bf16* __restrict__ W1t,
                           bf16* __restrict__ rW1t, bf16* __restrict__ W2t,
                           bf16* __restrict__ rW2t,
                           const int* __restrict__ dst, int* __restrict__ cursor) {
    if (blockIdx.y == 5) {   // edge count
        int e = blockIdx.x * 256 + threadIdx.x;
        if (e < NE) atomicAdd(&cursor[dst[e]], 1);
        return;
    }
    const float *W, *al, *ar; bf16* Wt; int K, M, rows, H, D;
    switch (blockIdx.y) {
        case 0: W = W0;  Wt = W0t;  K = 256; M = 128; rows = 144; H = 4; D = 32; al = al0; ar = ar0; break;
        case 1: W = W1;  Wt = W1t;  K = 128; M = 128; rows = 144; H = 4; D = 32; al = al1; ar = ar1; break;
        case 2: W = rW1; Wt = rW1t; K = 128; M = 128; rows = 128; H = 0; D = 0;  al = nullptr; ar = nullptr; break;
        case 3: W = W2;  Wt = W2t;  K = 128; M = 47;  rows = 64;  H = 1; D = 47; al = al2; ar = ar2; break;
        default: W = rW2; Wt = rW2t; K = 128; M = 47; rows = 48;  H = 0; D = 0;  al = nullptr; ar = nullptr; break;
    }
    int i = blockIdx.x * 256 + threadIdx.x;
    if (i >= rows * K) return;
    int row = i / K, k = i - row * K;
    float v = 0.f;
    if (row < M) {
        v = W[(long)k * M + row];
    } else if (H > 0 && row < M + 2 * H) {
        int idx = row - M;
        int h = (idx < H) ? idx : idx - H;
        const float* a = (idx < H) ? al : ar;
        float s = 0.f;
        for (int d = 0; d < D; ++d) s += W[(long)k * M + h * D + d] * a[h * D + d];
        v = s;
    }
    Wt[i] = __float2bfloat16(v);
}

// stage B: add scanned chunk bases; write offs (global) + cursor; offs[NN]=total
__global__ __launch_bounds__(256) void scanB(const int* __restrict__ bsum,
                                             int* __restrict__ offs,
                                             int* __restrict__ cursor) {
    __shared__ int bases[NCHUNKS + 1];
    if (threadIdx.x == 0) {
        int acc = 0;
        for (int j = 0; j < NCHUNKS; ++j) { bases[j] = acc; acc += bsum[j]; }
        bases[NCHUNKS] = acc;
    }
    __syncthreads();
    const int i = blockIdx.x * 256 + threadIdx.x;
    if (i < NN) {
        const int o = offs[i] + bases[i >> 10];
        offs[i] = o;
        cursor[i] = o;
    }
    if (i == 0) offs[NN] = bases[NCHUNKS];
}

// srcs[slot] = src id, in CSR-by-dst order
__global__ void fill_k(const int* __restrict__ dst, const int* __restrict__ src,
                       int* __restrict__ cursor, int* __restrict__ srcs, int E) {
    int e = blockIdx.x * blockDim.x + threadIdx.x;
    if (e < E) {
        int p = atomicAdd(&cursor[dst[e]], 1);
        srcs[p] = src[e];
    }
}

// ---- bf16 MFMA GEMM + fused attn projections, with optional tail blocks ----
// TAIL=0: none. TAIL=1: scanA (chunk-local exclusive scan of t_cnt, 256thr/1024elem).
// TAIL=2: e-score writer for a PREVIOUS layer (H=4 float4 tables pel/per -> eout).
template <bool A_F32, int NT1, int NT2, int HH, int TAIL>
__global__ __launch_bounds__(256) void gemm_mfma(
    const void* __restrict__ Av, const bf16* __restrict__ B1t,
    const bf16* __restrict__ B2t,
    bf16* __restrict__ C1b, float* __restrict__ el, float* __restrict__ er,
    float* __restrict__ C2, int N, int K, int M, int nGemmBlocks,
    const int* __restrict__ t_cnt, int* __restrict__ t_offs, int* __restrict__ t_bsum,
    const float4* __restrict__ pel, const float4* __restrict__ per,
    const int* __restrict__ src, const int* __restrict__ dst,
    float* __restrict__ eout) {
    constexpr int LP = 56;  // 32 k + pad: rows 112B (16B-aligned, 2-way alias = free)
    __shared__ bf16 As[64][LP];
    __shared__ bf16 Bs1[NT1 * 16][LP];
    __shared__ bf16 Bs2[(NT2 > 0) ? NT2 * 16 : 1][LP];
    __shared__ int ws4[4];

    const int tid = threadIdx.x;

    if constexpr (TAIL == 1) {
        if (blockIdx.x >= nGemmBlocks) {
            // chunk-local exclusive scan: 256 threads x 4 elems
            const int chunk = blockIdx.x - nGemmBlocks;
            const int lane = tid & 63;
            const int wid = tid >> 6;
            const int g = chunk * SCAN_CHUNK + tid * 4;
            const int a0 = (g + 0 < NN) ? t_cnt[g + 0] : 0;
            const int a1 = (g + 1 < NN) ? t_cnt[g + 1] : 0;
            const int a2 = (g + 2 < NN) ? t_cnt[g + 2] : 0;
            const int a3 = (g + 3 < NN) ? t_cnt[g + 3] : 0;
            const int lsum = a0 + a1 + a2 + a3;
            int x = lsum;
            #pragma unroll
            for (int off = 1; off < 64; off <<= 1) {
                int y = __shfl_up(x, off);
                if (lane >= off) x += y;
            }
            if (lane == 63) ws4[wid] = x;
            __syncthreads();
            int wbase = 0;
            #pragma unroll
            for (int j = 0; j < 4; ++j) if (j < wid) wbase += ws4[j];
            const int excl = wbase + x - lsum;
            if (g + 0 < NN) t_offs[g + 0] = excl;
            if (g + 1 < NN) t_offs[g + 1] = excl + a0;
            if (g + 2 < NN) t_offs[g + 2] = excl + a0 + a1;
            if (g + 3 < NN) t_offs[g + 3] = excl + a0 + a1 + a2;
            if (tid == 0) t_bsum[chunk] = ws4[0] + ws4[1] + ws4[2] + ws4[3];
            return;
        }
    }
    if constexpr (TAIL == 2) {
        if (blockIdx.x >= nGemmBlocks) {
            const int e = (blockIdx.x - nGemmBlocks) * 256 + tid;  // exact NE grid
            const int s = src[e], d = dst[e];
            const float4 a = pel[s], b = per[d];
            float4 v;
            v.x = lrelu(a.x + b.x); v.y = lrelu(a.y + b.y);
            v.z = lrelu(a.z + b.z); v.w = lrelu(a.w + b.w);
            *reinterpret_cast<float4*>(eout + e * 4) = v;
            return;
        }
    }

    const int lane = tid & 63;
    const int wid = tid >> 6;
    const int row0 = blockIdx.x * 64;
    const int l15 = lane & 15;
    const int kq = lane >> 4;          // k-quarter 0..3

    f32x4 acc1[NT1], acc2[(NT2 > 0) ? NT2 : 1];
    #pragma unroll
    for (int t = 0; t < NT1; ++t) acc1[t] = (f32x4){0.f, 0.f, 0.f, 0.f};
    if constexpr (NT2 > 0) {
        #pragma unroll
        for (int t = 0; t < NT2; ++t) acc2[t] = (f32x4){0.f, 0.f, 0.f, 0.f};
    }

    for (int k0 = 0; k0 < K; k0 += 32) {
        {
            const int r = tid >> 2, kk = (tid & 3) * 8;
            const int gr = row0 + r;
            if constexpr (A_F32) {
                const float* A = (const float*)Av;
                short tmp[8];
                if (gr < N) {
                    const float4 v0 = *(const float4*)&A[(long)gr * K + k0 + kk];
                    const float4 v1 = *(const float4*)&A[(long)gr * K + k0 + kk + 4];
                    tmp[0] = f2bf(v0.x); tmp[1] = f2bf(v0.y); tmp[2] = f2bf(v0.z); tmp[3] = f2bf(v0.w);
                    tmp[4] = f2bf(v1.x); tmp[5] = f2bf(v1.y); tmp[6] = f2bf(v1.z); tmp[7] = f2bf(v1.w);
                } else {
                    #pragma unroll
                    for (int j = 0; j < 8; ++j) tmp[j] = 0;
                }
                *(frag_ab*)&As[r][kk] = *(const frag_ab*)tmp;
            } else {
                const bf16* A = (const bf16*)Av;
                frag_ab v = {0, 0, 0, 0, 0, 0, 0, 0};
                if (gr < N) v = *(const frag_ab*)&A[(long)gr * K + k0 + kk];
                *(frag_ab*)&As[r][kk] = v;
            }
        }
        for (int i = tid; i < NT1 * 64; i += 256) {
            const int c = i >> 2, kk = (i & 3) * 8;
            *(frag_ab*)&Bs1[c][kk] = *(const frag_ab*)&B1t[(long)c * K + k0 + kk];
        }
        if constexpr (NT2 > 0) {
            for (int i = tid; i < NT2 * 64; i += 256) {
                const int c = i >> 2, kk = (i & 3) * 8;
                *(frag_ab*)&Bs2[c][kk] = *(const frag_ab*)&B2t[(long)c * K + k0 + kk];
            }
        }
        __syncthreads();

        const frag_ab a = *(const frag_ab*)&As[wid * 16 + l15][kq * 8];
        #pragma unroll
        for (int t = 0; t < NT1; ++t) {
            const frag_ab b = *(const frag_ab*)&Bs1[t * 16 + l15][kq * 8];
            acc1[t] = __builtin_amdgcn_mfma_f32_16x16x32_bf16(a, b, acc1[t], 0, 0, 0);
        }
        if constexpr (NT2 > 0) {
            #pragma unroll
            for (int t = 0; t < NT2; ++t) {
                const frag_ab b = *(const frag_ab*)&Bs2[t * 16 + l15][kq * 8];
                acc2[t] = __builtin_amdgcn_mfma_f32_16x16x32_bf16(a, b, acc2[t], 0, 0, 0);
            }
        }
        __syncthreads();
    }

    const int r0 = row0 + wid * 16 + kq * 4;
    #pragma unroll
    for (int t = 0; t < NT1; ++t) {
        const int c = t * 16 + l15;
        #pragma unroll
        for (int reg = 0; reg < 4; ++reg) {
            const int r = r0 + reg;
            if (r >= N) continue;
            const float v = acc1[t][reg];
            if (c < M) {
                C1b[(long)r * M + c] = __float2bfloat16(v);
            } else if (c < M + HH) {
                el[(long)r * HH + (c - M)] = v;
            } else if (c < M + 2 * HH) {
                er[(long)r * HH + (c - M - HH)] = v;
            }
        }
    }
    if constexpr (NT2 > 0) {
        #pragma unroll
        for (int t = 0; t < NT2; ++t) {
            const int c = t * 16 + l15;
            if (c >= M) continue;
            #pragma unroll
            for (int reg = 0; reg < 4; ++reg) {
                const int r = r0 + reg;
                if (r < N) C2[(long)r * M + c] = acc2[t][reg];
            }
        }
    }
}

// ---- node softmax + aggregation, one wave/node, H=4 D=32 (HD=128) ----
// Phase A (lane-strided): t = exp(lrelu(el[src]+er[node])), s += t;
//   first 64 edges cached in LDS; rest spill to global es (never in practice).
// Phase B (quarter-wave per edge): 16 lanes x ushort8 cover the 256B feat row;
//   4 quarters x 2-deep unroll = 8 gathers in flight.
template <int NELU, bool HAS_RES>
__global__ __launch_bounds__(256) void node_agg4(
    const bf16* __restrict__ featb, const float4* __restrict__ el4,
    const float4* __restrict__ er4, float4* __restrict__ es4,
    const int* __restrict__ offs, const int* __restrict__ srcs,
    const float* __restrict__ res, bf16* __restrict__ out) {
    __shared__ float4 sc[4][64];      // per-wave score cache (4 KB/wave)
    const int node = (int)((blockIdx.x * blockDim.x + threadIdx.x) >> 6);
    const int lane = threadIdx.x & 63;
    const int wid = threadIdx.x >> 6;
    const int beg = offs[node], end = offs[node + 1];
    const float4 ern = er4[node];   // wave-uniform

    // phase A
    float4 s4 = make_float4(0.f, 0.f, 0.f, 0.f);
    for (int i = beg + lane; i < end; i += 64) {
        const float4 elv = el4[srcs[i]];
        float4 t;
        t.x = expw(elv.x + ern.x); t.y = expw(elv.y + ern.y);
        t.z = expw(elv.z + ern.z); t.w = expw(elv.w + ern.w);
        s4.x += t.x; s4.y += t.y; s4.z += t.z; s4.w += t.w;
        const int idx = i - beg;
        if (idx < 64) sc[wid][idx] = t;
        else es4[i] = t;
    }
    #pragma unroll
    for (int off = 32; off > 0; off >>= 1) {
        s4.x += __shfl_xor(s4.x, off);
        s4.y += __shfl_xor(s4.y, off);
        s4.z += __shfl_xor(s4.z, off);
        s4.w += __shfl_xor(s4.w, off);
    }
    __syncthreads();   // orders spill stores + LDS writes before phase-B reads

    // phase B: quarter-wave per edge, ushort8 per lane
    const int q = lane >> 4;          // quarter 0..3
    const int l15 = lane & 15;
    const int fi = l15 * 8;           // 8 consecutive features (same head: 8|32)
    const int h = l15 >> 2;           // fi / 32
    const float sh = (h == 0) ? s4.x : (h == 1) ? s4.y : (h == 2) ? s4.z : s4.w;
    const float inv = 1.f / fmaxf(sh, 1e-9f);
    const float* esf = (const float*)es4;
    const float* scf = (const float*)sc[wid];

    float a[8] = {0.f, 0.f, 0.f, 0.f, 0.f, 0.f, 0.f, 0.f};
    int i = beg + q;
    for (; i + 4 < end; i += 8) {
        const int iB = i + 4;
        const int idxA = i - beg, idxB = iB - beg;
        const int snA = srcs[i], snB = srcs[iB];
        const float wA = (idxA < 64) ? scf[idxA * 4 + h] : esf[i * 4 + h];
        const float wB = (idxB < 64) ? scf[idxB * 4 + h] : esf[iB * 4 + h];
        const frag_ab fA = *(const frag_ab*)(featb + (long)snA * 128 + fi);
        const frag_ab fB = *(const frag_ab*)(featb + (long)snB * 128 + fi);
        #pragma unroll
        for (int j = 0; j < 8; ++j)
            a[j] += wA * b2f((unsigned short)fA[j]) + wB * b2f((unsigned short)fB[j]);
    }
    for (; i < end; i += 4) {
        const int idx = i - beg;
        const int sn = srcs[i];
        const float w = (idx < 64) ? scf[idx * 4 + h] : esf[i * 4 + h];
        const frag_ab f = *(const frag_ab*)(featb + (long)sn * 128 + fi);
        #pragma unroll
        for (int j = 0; j < 8; ++j) a[j] += w * b2f((unsigned short)f[j]);
    }
    #pragma unroll
    for (int j = 0; j < 8; ++j) {
        a[j] += __shfl_xor(a[j], 16);
        a[j] += __shfl_xor(a[j], 32);
    }

    if (lane < 16) {
        float v[8];
        #pragma unroll
        for (int j = 0; j < 8; ++j) v[j] = a[j] * inv;
        if constexpr (HAS_RES) {
            const float4 r0 = *(const float4*)(res + (long)node * 128 + fi);
            const float4 r1 = *(const float4*)(res + (long)node * 128 + fi + 4);
            v[0] += r0.x; v[1] += r0.y; v[2] += r0.z; v[3] += r0.w;
            v[4] += r1.x; v[5] += r1.y; v[6] += r1.z; v[7] += r1.w;
        }
        #pragma unroll
        for (int t = 0; t < NELU; ++t)
            #pragma unroll
            for (int j = 0; j < 8; ++j)
                v[j] = (v[j] > 0.f) ? v[j] : expm1f(v[j]);
        frag_ab o;
        #pragma unroll
        for (int j = 0; j < 8; ++j) o[j] = f2bf(v[j]);
        *(frag_ab*)(out + (long)node * 128 + fi) = o;
    }
}

// ---- final fused kernel: node_agg1 (blocks < NODE_BLKS) + e2 writes ----
__global__ __launch_bounds__(256) void final_k(
    const bf16* __restrict__ featb, const float* __restrict__ el2s,
    const float* __restrict__ er2s, float* __restrict__ es1,
    const int* __restrict__ offs, const int* __restrict__ srcs,
    const float* __restrict__ res, float* __restrict__ logits,
    const int* __restrict__ src, const int* __restrict__ dst,
    float* __restrict__ e2) {
    __shared__ float sc1[4][64];      // per-wave score cache (1 KB)
    if (blockIdx.x < NODE_BLKS) {
        const int node = (int)((blockIdx.x * blockDim.x + threadIdx.x) >> 6);
        const int lane = threadIdx.x & 63;
        const int wid = threadIdx.x >> 6;
        const int beg = offs[node], end = offs[node + 1];
        const float ern = er2s[node];

        float s = 0.f;
        for (int i = beg + lane; i < end; i += 64) {
            const float t = expw(el2s[srcs[i]] + ern);
            s += t;
            const int idx = i - beg;
            if (idx < 64) sc1[wid][idx] = t;
            else es1[i] = t;
        }
        #pragma unroll
        for (int off = 32; off > 0; off >>= 1) s += __shfl_xor(s, off);
        const float inv = 1.f / fmaxf(s, 1e-9f);
        __syncthreads();

        // aggregation with 8-deep unroll (8 gathers in flight)
        const bool active = lane < NC;
        float acc = 0.f;
        int i = beg;
        for (; i + 8 <= end; i += 8) {
            const int d0 = i - beg;
            int sn[8]; float w[8];
            #pragma unroll
            for (int k = 0; k < 8; ++k) {
                sn[k] = srcs[i + k];
                w[k] = (d0 + k < 64) ? sc1[wid][d0 + k] : es1[i + k];
            }
            if (active) {
                #pragma unroll
                for (int k = 0; k < 8; ++k)
                    acc += w[k] * __bfloat162float(featb[(long)sn[k] * NC + lane]);
            }
        }
        for (; i < end; ++i) {
            const int idx = i - beg;
            const float w = (idx < 64) ? sc1[wid][idx] : es1[i];
            if (active) acc += w * __bfloat162float(featb[(long)srcs[i] * NC + lane]);
        }
        if (active) {
            logits[(long)node * NC + lane] = acc * inv + res[(long)node * NC + lane];
        }
    } else {
        const int e = (blockIdx.x - NODE_BLKS) * 256 + threadIdx.x;  // exact NE
        e2[e] = lrelu(el2s[src[e]] + er2s[dst[e]]);
    }
}

extern "C" void kernel_launch(void* const* d_in, const int* in_sizes, int n_in,
                              void* d_out, int out_size, void* d_ws, size_t ws_size,
                              hipStream_t stream) {
    const float* x     = (const float*)d_in[0];
    const float* W0    = (const float*)d_in[1];
    const float* al0   = (const float*)d_in[2];
    const float* ar0   = (const float*)d_in[3];
    const float* W1    = (const float*)d_in[4];
    const float* resW1 = (const float*)d_in[5];
    const float* al1   = (const float*)d_in[6];
    const float* ar1   = (const float*)d_in[7];
    const float* W2    = (const float*)d_in[8];
    const float* resW2 = (const float*)d_in[9];
    const float* al2   = (const float*)d_in[10];
    const float* ar2   = (const float*)d_in[11];
    const int*   src   = (const int*)d_in[12];
    const int*   dst   = (const int*)d_in[13];

    float* out    = (float*)d_out;
    float* logits = out;                 // [N, 47]
    float* e0     = out + (long)NN * NC; // [E, 4]
    float* e1     = e0 + (long)NE * NH;  // [E, 4]
    float* e2     = e1 + (long)NE * NH;  // [E, 1]

    char* p = (char*)d_ws;
    int* offs   = (int*)p; p += align256(sizeof(int) * (NN + 1));
    int* cursor = (int*)p; p += align256(sizeof(int) * NN);
    int* bsum   = (int*)p; p += align256(sizeof(int) * 32);
    int* srcs   = (int*)p; p += align256(sizeof(int) * NE);
    float* el0b = (float*)p; p += align256(sizeof(float) * NN * NH);
    float* er0b = (float*)p; p += align256(sizeof(float) * NN * NH);
    float* el1b = (float*)p; p += align256(sizeof(float) * NN * NH);
    float* er1b = (float*)p; p += align256(sizeof(float) * NN * NH);
    float* el2b = (float*)p; p += align256(sizeof(float) * NN);
    float* er2b = (float*)p; p += align256(sizeof(float) * NN);
    float* es   = (float*)p; p += align256(sizeof(float) * (long)NE * NH);  // spill fallback
    float* resb = (float*)p; p += align256(sizeof(float) * (long)NN * 128);
    bf16* featb = (bf16*)p; p += align256(sizeof(bf16) * (long)NN * 128);
    bf16* hb    = (bf16*)p; p += align256(sizeof(bf16) * (long)NN * 128);
    bf16* W0t   = (bf16*)p; p += align256(sizeof(bf16) * 144 * 256);
    bf16* W1t   = (bf16*)p; p += align256(sizeof(bf16) * 144 * 128);
    bf16* rW1t  = (bf16*)p; p += align256(sizeof(bf16) * 128 * 128);
    bf16* W2t   = (bf16*)p; p += align256(sizeof(bf16) * 64 * 128);
    bf16* rW2t  = (bf16*)p; p += align256(sizeof(bf16) * 48 * 128);

    const int gemmBlocks = (NN + 63) / 64;   // 469

    // ---- 1: zero cursor; 2: prep weights ∥ count edges ----
    hipMemsetAsync(cursor, 0, sizeof(int) * NN, stream);
    prep_count<<<dim3(EDGE_BLKS, 6), 256, 0, stream>>>(
        W0, W1, resW1, W2, resW2, al0, ar0, al1, ar1, al2, ar2,
        W0t, W1t, rW1t, W2t, rW2t, dst, cursor);

    // ---- 3: gemm0 ∥ scanA (chunk-local scans hidden under layer-0 GEMM) ----
    gemm_mfma<true, 9, 0, NH, 1><<<gemmBlocks + NCHUNKS, 256, 0, stream>>>(
        x, W0t, nullptr, featb, el0b, er0b, nullptr, NN, FIN, 128, gemmBlocks,
        cursor, offs, bsum, nullptr, nullptr, nullptr, nullptr, nullptr);

    // ---- 4: scanB (add chunk bases, write cursor) ; 5: fill ----
    scanB<<<(NN + 255) / 256, 256, 0, stream>>>(bsum, offs, cursor);
    fill_k<<<EDGE_BLKS, 256, 0, stream>>>(dst, src, cursor, srcs, NE);

    // ---- 6: layer-0 aggregation ----
    node_agg4<1, false><<<NODE_BLKS, 256, 0, stream>>>(
        featb, (const float4*)el0b, (const float4*)er0b, (float4*)es, offs, srcs, nullptr, hb);

    // ---- 7: gemm1 (dual) ∥ e0 writes ----
    gemm_mfma<false, 9, 8, NH, 2><<<gemmBlocks + EDGE_BLKS, 256, 0, stream>>>(
        hb, W1t, rW1t, featb, el1b, er1b, resb, NN, 128, 128, gemmBlocks,
        nullptr, nullptr, nullptr,
        (const float4*)el0b, (const float4*)er0b, src, dst, e0);

    // ---- 8: layer-1 aggregation ----
    node_agg4<2, true><<<NODE_BLKS, 256, 0, stream>>>(
        featb, (const float4*)el1b, (const float4*)er1b, (float4*)es, offs, srcs, resb, hb);

    // ---- 9: gemm2 (dual, M=47) ∥ e1 writes ----
    gemm_mfma<false, 4, 3, 1, 2><<<gemmBlocks + EDGE_BLKS, 256, 0, stream>>>(
        hb, W2t, rW2t, featb, el2b, er2b, resb, NN, 128, NC, gemmBlocks,
        nullptr, nullptr, nullptr,
        (const float4*)el1b, (const float4*)er1b, src, dst, e1);

    // ---- 10: node_agg1 (logits) ∥ e2 writes ----
    final_k<<<NODE_BLKS + EDGE_BLKS, 256, 0, stream>>>(
        featb, el2b, er2b, es, offs, srcs, resb, logits, src, dst, e2);
}

// Round 13
// 182.531 us; speedup vs baseline: 1.3893x; 1.1048x over previous
//
#include <hip/hip_runtime.h>
#include <hip/hip_bf16.h>
#include <math.h>

// Problem constants
#define NN 30000
#define NE 480000
#define FIN 256
#define DH 32
#define NH 4
#define NC 47
#define NODE_BLKS 7500   // NN/4 (4 waves/block, 1 wave/node)
#define EDGE_BLKS 1875   // NE/256
#define SCAN_CHUNK 1024  // 30 chunks of 1024 (30720 >= 30000)
#define NCHUNKS 30

typedef __attribute__((ext_vector_type(8))) short frag_ab;  // 8 bf16 (4 VGPR)
typedef __attribute__((ext_vector_type(4))) float f32x4;    // MFMA 16x16 accum
typedef __hip_bfloat16 bf16;

static inline size_t align256(size_t x) { return (x + 255) & ~(size_t)255; }

__device__ __forceinline__ short f2bf(float f) {
    union { float f; unsigned u; } c; c.f = f;
    unsigned r = (c.u + 0x7FFFu + ((c.u >> 16) & 1u)) >> 16;  // RNE
    return (short)r;
}
__device__ __forceinline__ float b2f(unsigned short u) {
    union { unsigned u; float f; } c; c.u = (unsigned)u << 16; return c.f;
}
// exp(leaky_relu(v)) — no max subtraction (scores O(10), far from f32 overflow)
__device__ __forceinline__ float expw(float v) {
    return __expf((v >= 0.f) ? v : 0.2f * v);
}
__device__ __forceinline__ float lrelu(float v) {
    return (v >= 0.f) ? v : 0.2f * v;
}

// ---- weight prep (y<5) ∥ CSR count+rank (y==5). cnt zeroed beforehand.
// rank[e] = this edge's arrival index among edges with the same dst.
__global__ void prep_count(const float* __restrict__ W0, const float* __restrict__ W1,
                           const float* __restrict__ rW1, const float* __restrict__ W2,
                           const float* __restrict__ rW2,
                           const float* __restrict__ al0, const float* __restrict__ ar0,
                           const float* __restrict__ al1, const float* __restrict__ ar1,
                           const float* __restrict__ al2, const float* __restrict__ ar2,
                           bf16* __restrict__ W0t, bf16* __restrict__ W1t,
                           bf16* __restrict__ rW1t, bf16* __restrict__ W2t,
                           bf16* __restrict__ rW2t,
                           const int* __restrict__ dst, int* __restrict__ cnt,
                           int* __restrict__ rank) {
    if (blockIdx.y == 5) {   // edge count + rank
        int e = blockIdx.x * 256 + threadIdx.x;
        if (e < NE) rank[e] = atomicAdd(&cnt[dst[e]], 1);
        return;
    }
    const float *W, *al, *ar; bf16* Wt; int K, M, rows, H, D;
    switch (blockIdx.y) {
        case 0: W = W0;  Wt = W0t;  K = 256; M = 128; rows = 144; H = 4; D = 32; al = al0; ar = ar0; break;
        case 1: W = W1;  Wt = W1t;  K = 128; M = 128; rows = 144; H = 4; D = 32; al = al1; ar = ar1; break;
        case 2: W = rW1; Wt = rW1t; K = 128; M = 128; rows = 128; H = 0; D = 0;  al = nullptr; ar = nullptr; break;
        case 3: W = W2;  Wt = W2t;  K = 128; M = 47;  rows = 64;  H = 1; D = 47; al = al2; ar = ar2; break;
        default: W = rW2; Wt = rW2t; K = 128; M = 47; rows = 48;  H = 0; D = 0;  al = nullptr; ar = nullptr; break;
    }
    int i = blockIdx.x * 256 + threadIdx.x;
    if (i >= rows * K) return;
    int row = i / K, k = i - row * K;
    float v = 0.f;
    if (row < M) {
        v = W[(long)k * M + row];
    } else if (H > 0 && row < M + 2 * H) {
        int idx = row - M;
        int h = (idx < H) ? idx : idx - H;
        const float* a = (idx < H) ? al : ar;
        float s = 0.f;
        for (int d = 0; d < D; ++d) s += W[(long)k * M + h * D + d] * a[h * D + d];
        v = s;
    }
    Wt[i] = __float2bfloat16(v);
}

// srcs[slot] = src id, in CSR-by-dst order. Atomic-free (rank precomputed).
__global__ void fill_k(const int* __restrict__ dst, const int* __restrict__ src,
                       const int* __restrict__ rank, const int* __restrict__ loff,
                       const int* __restrict__ bases, int* __restrict__ srcs) {
    int e = blockIdx.x * blockDim.x + threadIdx.x;
    if (e < NE) {
        const int d = dst[e];
        srcs[loff[d] + bases[d >> 10] + rank[e]] = src[e];
    }
}

// ---- bf16 MFMA GEMM + fused attn projections, with optional tail blocks ----
// TAIL=0: none. TAIL=1: scanA (chunk-local exclusive scan of t_cnt); last
//   finishing chunk scans bsum -> bases (device-scope done counter).
// TAIL=2: e-score writer for a PREVIOUS layer (H=4 float4 tables pel/per -> eout).
template <bool A_F32, int NT1, int NT2, int HH, int TAIL>
__global__ __launch_bounds__(256) void gemm_mfma(
    const void* __restrict__ Av, const bf16* __restrict__ B1t,
    const bf16* __restrict__ B2t,
    bf16* __restrict__ C1b, float* __restrict__ el, float* __restrict__ er,
    bf16* __restrict__ C2, int N, int K, int M, int nGemmBlocks,
    const int* __restrict__ t_cnt, int* __restrict__ t_loff, int* __restrict__ t_bsum,
    int* __restrict__ t_bases, int* __restrict__ t_done,
    const float4* __restrict__ pel, const float4* __restrict__ per,
    const int* __restrict__ src, const int* __restrict__ dst,
    float* __restrict__ eout) {
    constexpr int LP = 56;  // 32 k + pad: rows 112B (16B-aligned, 2-way alias = free)
    __shared__ bf16 As[64][LP];
    __shared__ bf16 Bs1[NT1 * 16][LP];
    __shared__ bf16 Bs2[(NT2 > 0) ? NT2 * 16 : 1][LP];
    __shared__ int ws4[4];

    const int tid = threadIdx.x;

    if constexpr (TAIL == 1) {
        if (blockIdx.x >= nGemmBlocks) {
            // chunk-local exclusive scan: 256 threads x 4 elems
            const int chunk = blockIdx.x - nGemmBlocks;
            const int lane = tid & 63;
            const int wid = tid >> 6;
            const int g = chunk * SCAN_CHUNK + tid * 4;
            const int a0 = (g + 0 < NN) ? t_cnt[g + 0] : 0;
            const int a1 = (g + 1 < NN) ? t_cnt[g + 1] : 0;
            const int a2 = (g + 2 < NN) ? t_cnt[g + 2] : 0;
            const int a3 = (g + 3 < NN) ? t_cnt[g + 3] : 0;
            const int lsum = a0 + a1 + a2 + a3;
            int x = lsum;
            #pragma unroll
            for (int off = 1; off < 64; off <<= 1) {
                int y = __shfl_up(x, off);
                if (lane >= off) x += y;
            }
            if (lane == 63) ws4[wid] = x;
            __syncthreads();
            int wbase = 0;
            #pragma unroll
            for (int j = 0; j < 4; ++j) if (j < wid) wbase += ws4[j];
            const int excl = wbase + x - lsum;
            if (g + 0 < NN) t_loff[g + 0] = excl;
            if (g + 1 < NN) t_loff[g + 1] = excl + a0;
            if (g + 2 < NN) t_loff[g + 2] = excl + a0 + a1;
            if (g + 3 < NN) t_loff[g + 3] = excl + a0 + a1 + a2;
            if (tid == 0) {
                t_bsum[chunk] = ws4[0] + ws4[1] + ws4[2] + ws4[3];
                __threadfence();                       // publish bsum + loff
                const int prev = atomicAdd(t_done, 1);
                if (prev == NCHUNKS - 1) {             // last chunk: scan bases
                    __threadfence();                   // acquire others' bsum
                    int acc = 0;
                    for (int j = 0; j < NCHUNKS; ++j) { t_bases[j] = acc; acc += t_bsum[j]; }
                    t_bases[NCHUNKS] = acc;
                }
            }
            return;
        }
    }
    if constexpr (TAIL == 2) {
        if (blockIdx.x >= nGemmBlocks) {
            const int e = (blockIdx.x - nGemmBlocks) * 256 + tid;  // exact NE grid
            const int s = src[e], d = dst[e];
            const float4 a = pel[s], b = per[d];
            float4 v;
            v.x = lrelu(a.x + b.x); v.y = lrelu(a.y + b.y);
            v.z = lrelu(a.z + b.z); v.w = lrelu(a.w + b.w);
            *reinterpret_cast<float4*>(eout + e * 4) = v;
            return;
        }
    }

    const int lane = tid & 63;
    const int wid = tid >> 6;
    const int row0 = blockIdx.x * 64;
    const int l15 = lane & 15;
    const int kq = lane >> 4;          // k-quarter 0..3

    f32x4 acc1[NT1], acc2[(NT2 > 0) ? NT2 : 1];
    #pragma unroll
    for (int t = 0; t < NT1; ++t) acc1[t] = (f32x4){0.f, 0.f, 0.f, 0.f};
    if constexpr (NT2 > 0) {
        #pragma unroll
        for (int t = 0; t < NT2; ++t) acc2[t] = (f32x4){0.f, 0.f, 0.f, 0.f};
    }

    for (int k0 = 0; k0 < K; k0 += 32) {
        {
            const int r = tid >> 2, kk = (tid & 3) * 8;
            const int gr = row0 + r;
            if constexpr (A_F32) {
                const float* A = (const float*)Av;
                short tmp[8];
                if (gr < N) {
                    const float4 v0 = *(const float4*)&A[(long)gr * K + k0 + kk];
                    const float4 v1 = *(const float4*)&A[(long)gr * K + k0 + kk + 4];
                    tmp[0] = f2bf(v0.x); tmp[1] = f2bf(v0.y); tmp[2] = f2bf(v0.z); tmp[3] = f2bf(v0.w);
                    tmp[4] = f2bf(v1.x); tmp[5] = f2bf(v1.y); tmp[6] = f2bf(v1.z); tmp[7] = f2bf(v1.w);
                } else {
                    #pragma unroll
                    for (int j = 0; j < 8; ++j) tmp[j] = 0;
                }
                *(frag_ab*)&As[r][kk] = *(const frag_ab*)tmp;
            } else {
                const bf16* A = (const bf16*)Av;
                frag_ab v = {0, 0, 0, 0, 0, 0, 0, 0};
                if (gr < N) v = *(const frag_ab*)&A[(long)gr * K + k0 + kk];
                *(frag_ab*)&As[r][kk] = v;
            }
        }
        for (int i = tid; i < NT1 * 64; i += 256) {
            const int c = i >> 2, kk = (i & 3) * 8;
            *(frag_ab*)&Bs1[c][kk] = *(const frag_ab*)&B1t[(long)c * K + k0 + kk];
        }
        if constexpr (NT2 > 0) {
            for (int i = tid; i < NT2 * 64; i += 256) {
                const int c = i >> 2, kk = (i & 3) * 8;
                *(frag_ab*)&Bs2[c][kk] = *(const frag_ab*)&B2t[(long)c * K + k0 + kk];
            }
        }
        __syncthreads();

        const frag_ab a = *(const frag_ab*)&As[wid * 16 + l15][kq * 8];
        #pragma unroll
        for (int t = 0; t < NT1; ++t) {
            const frag_ab b = *(const frag_ab*)&Bs1[t * 16 + l15][kq * 8];
            acc1[t] = __builtin_amdgcn_mfma_f32_16x16x32_bf16(a, b, acc1[t], 0, 0, 0);
        }
        if constexpr (NT2 > 0) {
            #pragma unroll
            for (int t = 0; t < NT2; ++t) {
                const frag_ab b = *(const frag_ab*)&Bs2[t * 16 + l15][kq * 8];
                acc2[t] = __builtin_amdgcn_mfma_f32_16x16x32_bf16(a, b, acc2[t], 0, 0, 0);
            }
        }
        __syncthreads();
    }

    const int r0 = row0 + wid * 16 + kq * 4;
    #pragma unroll
    for (int t = 0; t < NT1; ++t) {
        const int c = t * 16 + l15;
        #pragma unroll
        for (int reg = 0; reg < 4; ++reg) {
            const int r = r0 + reg;
            if (r >= N) continue;
            const float v = acc1[t][reg];
            if (c < M) {
                C1b[(long)r * M + c] = __float2bfloat16(v);
            } else if (c < M + HH) {
                el[(long)r * HH + (c - M)] = v;
            } else if (c < M + 2 * HH) {
                er[(long)r * HH + (c - M - HH)] = v;
            }
        }
    }
    if constexpr (NT2 > 0) {
        #pragma unroll
        for (int t = 0; t < NT2; ++t) {
            const int c = t * 16 + l15;
            if (c >= M) continue;
            #pragma unroll
            for (int reg = 0; reg < 4; ++reg) {
                const int r = r0 + reg;
                if (r < N) C2[(long)r * M + c] = __float2bfloat16(acc2[t][reg]);
            }
        }
    }
}

// ---- node softmax + aggregation, one wave/node, H=4 D=32 (HD=128) ----
// beg/end computed from chunk-local loff + bases (no materialized offs).
template <int NELU, bool HAS_RES>
__global__ __launch_bounds__(256) void node_agg4(
    const bf16* __restrict__ featb, const float4* __restrict__ el4,
    const float4* __restrict__ er4, float4* __restrict__ es4,
    const int* __restrict__ loff, const int* __restrict__ bases,
    const int* __restrict__ srcs,
    const bf16* __restrict__ res, bf16* __restrict__ out) {
    __shared__ float4 sc[4][64];      // per-wave score cache (4 KB/wave)
    const int node = (int)((blockIdx.x * blockDim.x + threadIdx.x) >> 6);
    const int lane = threadIdx.x & 63;
    const int wid = threadIdx.x >> 6;
    const int beg = loff[node] + bases[node >> 10];
    const int end = (node == NN - 1) ? NE : loff[node + 1] + bases[(node + 1) >> 10];
    const float4 ern = er4[node];   // wave-uniform

    // phase A
    float4 s4 = make_float4(0.f, 0.f, 0.f, 0.f);
    for (int i = beg + lane; i < end; i += 64) {
        const float4 elv = el4[srcs[i]];
        float4 t;
        t.x = expw(elv.x + ern.x); t.y = expw(elv.y + ern.y);
        t.z = expw(elv.z + ern.z); t.w = expw(elv.w + ern.w);
        s4.x += t.x; s4.y += t.y; s4.z += t.z; s4.w += t.w;
        const int idx = i - beg;
        if (idx < 64) sc[wid][idx] = t;
        else es4[i] = t;
    }
    #pragma unroll
    for (int off = 32; off > 0; off >>= 1) {
        s4.x += __shfl_xor(s4.x, off);
        s4.y += __shfl_xor(s4.y, off);
        s4.z += __shfl_xor(s4.z, off);
        s4.w += __shfl_xor(s4.w, off);
    }
    __syncthreads();   // orders spill stores + LDS writes before phase-B reads

    // phase B: quarter-wave per edge, ushort8 per lane
    const int q = lane >> 4;          // quarter 0..3
    const int l15 = lane & 15;
    const int fi = l15 * 8;           // 8 consecutive features (same head: 8|32)
    const int h = l15 >> 2;           // fi / 32
    const float sh = (h == 0) ? s4.x : (h == 1) ? s4.y : (h == 2) ? s4.z : s4.w;
    const float inv = 1.f / fmaxf(sh, 1e-9f);
    const float* esf = (const float*)es4;
    const float* scf = (const float*)sc[wid];

    float a[8] = {0.f, 0.f, 0.f, 0.f, 0.f, 0.f, 0.f, 0.f};
    int i = beg + q;
    for (; i + 4 < end; i += 8) {
        const int iB = i + 4;
        const int idxA = i - beg, idxB = iB - beg;
        const int snA = srcs[i], snB = srcs[iB];
        const float wA = (idxA < 64) ? scf[idxA * 4 + h] : esf[i * 4 + h];
        const float wB = (idxB < 64) ? scf[idxB * 4 + h] : esf[iB * 4 + h];
        const frag_ab fA = *(const frag_ab*)(featb + (long)snA * 128 + fi);
        const frag_ab fB = *(const frag_ab*)(featb + (long)snB * 128 + fi);
        #pragma unroll
        for (int j = 0; j < 8; ++j)
            a[j] += wA * b2f((unsigned short)fA[j]) + wB * b2f((unsigned short)fB[j]);
    }
    for (; i < end; i += 4) {
        const int idx = i - beg;
        const int sn = srcs[i];
        const float w = (idx < 64) ? scf[idx * 4 + h] : esf[i * 4 + h];
        const frag_ab f = *(const frag_ab*)(featb + (long)sn * 128 + fi);
        #pragma unroll
        for (int j = 0; j < 8; ++j) a[j] += w * b2f((unsigned short)f[j]);
    }
    #pragma unroll
    for (int j = 0; j < 8; ++j) {
        a[j] += __shfl_xor(a[j], 16);
        a[j] += __shfl_xor(a[j], 32);
    }

    if (lane < 16) {
        float v[8];
        #pragma unroll
        for (int j = 0; j < 8; ++j) v[j] = a[j] * inv;
        if constexpr (HAS_RES) {
            const frag_ab rr = *(const frag_ab*)(res + (long)node * 128 + fi);
            #pragma unroll
            for (int j = 0; j < 8; ++j) v[j] += b2f((unsigned short)rr[j]);
        }
        #pragma unroll
        for (int t = 0; t < NELU; ++t)
            #pragma unroll
            for (int j = 0; j < 8; ++j)
                v[j] = (v[j] > 0.f) ? v[j] : expm1f(v[j]);
        frag_ab o;
        #pragma unroll
        for (int j = 0; j < 8; ++j) o[j] = f2bf(v[j]);
        *(frag_ab*)(out + (long)node * 128 + fi) = o;
    }
}

// ---- final fused kernel: node_agg1 (blocks < NODE_BLKS) + e2 writes ----
__global__ __launch_bounds__(256) void final_k(
    const bf16* __restrict__ featb, const float* __restrict__ el2s,
    const float* __restrict__ er2s, float* __restrict__ es1,
    const int* __restrict__ loff, const int* __restrict__ bases,
    const int* __restrict__ srcs,
    const bf16* __restrict__ res, float* __restrict__ logits,
    const int* __restrict__ src, const int* __restrict__ dst,
    float* __restrict__ e2) {
    __shared__ float sc1[4][64];      // per-wave score cache (1 KB)
    if (blockIdx.x < NODE_BLKS) {
        const int node = (int)((blockIdx.x * blockDim.x + threadIdx.x) >> 6);
        const int lane = threadIdx.x & 63;
        const int wid = threadIdx.x >> 6;
        const int beg = loff[node] + bases[node >> 10];
        const int end = (node == NN - 1) ? NE : loff[node + 1] + bases[(node + 1) >> 10];
        const float ern = er2s[node];

        float s = 0.f;
        for (int i = beg + lane; i < end; i += 64) {
            const float t = expw(el2s[srcs[i]] + ern);
            s += t;
            const int idx = i - beg;
            if (idx < 64) sc1[wid][idx] = t;
            else es1[i] = t;
        }
        #pragma unroll
        for (int off = 32; off > 0; off >>= 1) s += __shfl_xor(s, off);
        const float inv = 1.f / fmaxf(s, 1e-9f);
        __syncthreads();

        // aggregation with 8-deep unroll (8 gathers in flight)
        const bool active = lane < NC;
        float acc = 0.f;
        int i = beg;
        for (; i + 8 <= end; i += 8) {
            const int d0 = i - beg;
            int sn[8]; float w[8];
            #pragma unroll
            for (int k = 0; k < 8; ++k) {
                sn[k] = srcs[i + k];
                w[k] = (d0 + k < 64) ? sc1[wid][d0 + k] : es1[i + k];
            }
            if (active) {
                #pragma unroll
                for (int k = 0; k < 8; ++k)
                    acc += w[k] * __bfloat162float(featb[(long)sn[k] * NC + lane]);
            }
        }
        for (; i < end; ++i) {
            const int idx = i - beg;
            const float w = (idx < 64) ? sc1[wid][idx] : es1[i];
            if (active) acc += w * __bfloat162float(featb[(long)srcs[i] * NC + lane]);
        }
        if (active) {
            logits[(long)node * NC + lane] =
                acc * inv + __bfloat162float(res[(long)node * NC + lane]);
        }
    } else {
        const int e = (blockIdx.x - NODE_BLKS) * 256 + threadIdx.x;  // exact NE
        e2[e] = lrelu(el2s[src[e]] + er2s[dst[e]]);
    }
}

extern "C" void kernel_launch(void* const* d_in, const int* in_sizes, int n_in,
                              void* d_out, int out_size, void* d_ws, size_t ws_size,
                              hipStream_t stream) {
    const float* x     = (const float*)d_in[0];
    const float* W0    = (const float*)d_in[1];
    const float* al0   = (const float*)d_in[2];
    const float* ar0   = (const float*)d_in[3];
    const float* W1    = (const float*)d_in[4];
    const float* resW1 = (const float*)d_in[5];
    const float* al1   = (const float*)d_in[6];
    const float* ar1   = (const float*)d_in[7];
    const float* W2    = (const float*)d_in[8];
    const float* resW2 = (const float*)d_in[9];
    const float* al2   = (const float*)d_in[10];
    const float* ar2   = (const float*)d_in[11];
    const int*   src   = (const int*)d_in[12];
    const int*   dst   = (const int*)d_in[13];

    float* out    = (float*)d_out;
    float* logits = out;                 // [N, 47]
    float* e0     = out + (long)NN * NC; // [E, 4]
    float* e1     = e0 + (long)NE * NH;  // [E, 4]
    float* e2     = e1 + (long)NE * NH;  // [E, 1]

    char* p = (char*)d_ws;
    int* cnt    = (int*)p; p += align256(sizeof(int) * (NN + 64));  // cnt + done ctr
    int* done   = cnt + NN;
    int* loff   = (int*)p; p += align256(sizeof(int) * (NN + 1));
    int* bsum   = (int*)p; p += align256(sizeof(int) * 32);
    int* bases  = (int*)p; p += align256(sizeof(int) * 32);
    int* rank   = (int*)p; p += align256(sizeof(int) * NE);
    int* srcs   = (int*)p; p += align256(sizeof(int) * NE);
    float* el0b = (float*)p; p += align256(sizeof(float) * NN * NH);
    float* er0b = (float*)p; p += align256(sizeof(float) * NN * NH);
    float* el1b = (float*)p; p += align256(sizeof(float) * NN * NH);
    float* er1b = (float*)p; p += align256(sizeof(float) * NN * NH);
    float* el2b = (float*)p; p += align256(sizeof(float) * NN);
    float* er2b = (float*)p; p += align256(sizeof(float) * NN);
    float* es   = (float*)p; p += align256(sizeof(float) * (long)NE * NH);  // spill fallback
    bf16* resb  = (bf16*)p; p += align256(sizeof(bf16) * (long)NN * 128);
    bf16* featb = (bf16*)p; p += align256(sizeof(bf16) * (long)NN * 128);
    bf16* hb    = (bf16*)p; p += align256(sizeof(bf16) * (long)NN * 128);
    bf16* W0t   = (bf16*)p; p += align256(sizeof(bf16) * 144 * 256);
    bf16* W1t   = (bf16*)p; p += align256(sizeof(bf16) * 144 * 128);
    bf16* rW1t  = (bf16*)p; p += align256(sizeof(bf16) * 128 * 128);
    bf16* W2t   = (bf16*)p; p += align256(sizeof(bf16) * 64 * 128);
    bf16* rW2t  = (bf16*)p; p += align256(sizeof(bf16) * 48 * 128);

    const int gemmBlocks = (NN + 63) / 64;   // 469

    // ---- 1: zero cnt+done; 2: prep weights ∥ count+rank ----
    hipMemsetAsync(cnt, 0, sizeof(int) * (NN + 64), stream);
    prep_count<<<dim3(EDGE_BLKS, 6), 256, 0, stream>>>(
        W0, W1, resW1, W2, resW2, al0, ar0, al1, ar1, al2, ar2,
        W0t, W1t, rW1t, W2t, rW2t, dst, cnt, rank);

    // ---- 3: gemm0 ∥ scanA (chunk scans + bases, hidden under layer-0 GEMM) ----
    gemm_mfma<true, 9, 0, NH, 1><<<gemmBlocks + NCHUNKS, 256, 0, stream>>>(
        x, W0t, nullptr, featb, el0b, er0b, nullptr, NN, FIN, 128, gemmBlocks,
        cnt, loff, bsum, bases, done, nullptr, nullptr, nullptr, nullptr, nullptr);

    // ---- 4: fill (atomic-free, rank-based) ----
    fill_k<<<EDGE_BLKS, 256, 0, stream>>>(dst, src, rank, loff, bases, srcs);

    // ---- 5: layer-0 aggregation ----
    node_agg4<1, false><<<NODE_BLKS, 256, 0, stream>>>(
        featb, (const float4*)el0b, (const float4*)er0b, (float4*)es,
        loff, bases, srcs, nullptr, hb);

    // ---- 6: gemm1 (dual) ∥ e0 writes ----
    gemm_mfma<false, 9, 8, NH, 2><<<gemmBlocks + EDGE_BLKS, 256, 0, stream>>>(
        hb, W1t, rW1t, featb, el1b, er1b, resb, NN, 128, 128, gemmBlocks,
        nullptr, nullptr, nullptr, nullptr, nullptr,
        (const float4*)el0b, (const float4*)er0b, src, dst, e0);

    // ---- 7: layer-1 aggregation ----
    node_agg4<2, true><<<NODE_BLKS, 256, 0, stream>>>(
        featb, (const float4*)el1b, (const float4*)er1b, (float4*)es,
        loff, bases, srcs, resb, hb);

    // ---- 8: gemm2 (dual, M=47) ∥ e1 writes ----
    gemm_mfma<false, 4, 3, 1, 2><<<gemmBlocks + EDGE_BLKS, 256, 0, stream>>>(
        hb, W2t, rW2t, featb, el2b, er2b, resb, NN, 128, NC, gemmBlocks,
        nullptr, nullptr, nullptr, nullptr, nullptr,
        (const float4*)el1b, (const float4*)er1b, src, dst, e1);

    // ---- 9: node_agg1 (logits) ∥ e2 writes ----
    final_k<<<NODE_BLKS + EDGE_BLKS, 256, 0, stream>>>(
        featb, el2b, er2b, es, loff, bases, srcs, resb, logits, src, dst, e2);
}

// Round 14
// 178.042 us; speedup vs baseline: 1.4243x; 1.0252x over previous
//
#include <hip/hip_runtime.h>
#include <hip/hip_bf16.h>
#include <math.h>

// Problem constants
#define NN 30000
#define NE 480000
#define FIN 256
#define DH 32
#define NH 4
#define NC 47
#define NODE_BLKS 7500   // NN/4 (4 waves/block, 1 wave/node)
#define EDGE_BLKS 1875   // NE/256
#define SCAN_CHUNK 1024  // 30 chunks of 1024 (30720 >= 30000)
#define NCHUNKS 30

typedef __attribute__((ext_vector_type(8))) short frag_ab;  // 8 bf16 (4 VGPR)
typedef __attribute__((ext_vector_type(4))) float f32x4;    // MFMA 16x16 accum
typedef __hip_bfloat16 bf16;

static inline size_t align256(size_t x) { return (x + 255) & ~(size_t)255; }

__device__ __forceinline__ short f2bf(float f) {
    union { float f; unsigned u; } c; c.f = f;
    unsigned r = (c.u + 0x7FFFu + ((c.u >> 16) & 1u)) >> 16;  // RNE
    return (short)r;
}
__device__ __forceinline__ float b2f(unsigned short u) {
    union { unsigned u; float f; } c; c.u = (unsigned)u << 16; return c.f;
}
// exp(leaky_relu(v)) — no max subtraction (scores O(10), far from f32 overflow)
__device__ __forceinline__ float expw(float v) {
    return __expf((v >= 0.f) ? v : 0.2f * v);
}
__device__ __forceinline__ float lrelu(float v) {
    return (v >= 0.f) ? v : 0.2f * v;
}

// ---- weight prep (y<5) ∥ CSR count+rank (y==5). cnt zeroed beforehand.
// rank[e] = this edge's arrival index among edges with the same dst.
__global__ void prep_count(const float* __restrict__ W0, const float* __restrict__ W1,
                           const float* __restrict__ rW1, const float* __restrict__ W2,
                           const float* __restrict__ rW2,
                           const float* __restrict__ al0, const float* __restrict__ ar0,
                           const float* __restrict__ al1, const float* __restrict__ ar1,
                           const float* __restrict__ al2, const float* __restrict__ ar2,
                           bf16* __restrict__ W0t, bf16* __restrict__ W1t,
                           bf16* __restrict__ rW1t, bf16* __restrict__ W2t,
                           bf16* __restrict__ rW2t,
                           const int* __restrict__ dst, int* __restrict__ cnt,
                           int* __restrict__ rank) {
    if (blockIdx.y == 5) {   // edge count + rank
        int e = blockIdx.x * 256 + threadIdx.x;
        if (e < NE) rank[e] = atomicAdd(&cnt[dst[e]], 1);
        return;
    }
    const float *W, *al, *ar; bf16* Wt; int K, M, rows, H, D;
    switch (blockIdx.y) {
        case 0: W = W0;  Wt = W0t;  K = 256; M = 128; rows = 144; H = 4; D = 32; al = al0; ar = ar0; break;
        case 1: W = W1;  Wt = W1t;  K = 128; M = 128; rows = 144; H = 4; D = 32; al = al1; ar = ar1; break;
        case 2: W = rW1; Wt = rW1t; K = 128; M = 128; rows = 128; H = 0; D = 0;  al = nullptr; ar = nullptr; break;
        case 3: W = W2;  Wt = W2t;  K = 128; M = 47;  rows = 64;  H = 1; D = 47; al = al2; ar = ar2; break;
        default: W = rW2; Wt = rW2t; K = 128; M = 47; rows = 48;  H = 0; D = 0;  al = nullptr; ar = nullptr; break;
    }
    int i = blockIdx.x * 256 + threadIdx.x;
    if (i >= rows * K) return;
    int row = i / K, k = i - row * K;
    float v = 0.f;
    if (row < M) {
        v = W[(long)k * M + row];
    } else if (H > 0 && row < M + 2 * H) {
        int idx = row - M;
        int h = (idx < H) ? idx : idx - H;
        const float* a = (idx < H) ? al : ar;
        float s = 0.f;
        for (int d = 0; d < D; ++d) s += W[(long)k * M + h * D + d] * a[h * D + d];
        v = s;
    }
    Wt[i] = __float2bfloat16(v);
}

// srcs[slot] = src id, in CSR-by-dst order. Atomic-free (rank precomputed).
__global__ void fill_k(const int* __restrict__ dst, const int* __restrict__ src,
                       const int* __restrict__ rank, const int* __restrict__ loff,
                       const int* __restrict__ bases, int* __restrict__ srcs) {
    int e = blockIdx.x * blockDim.x + threadIdx.x;
    if (e < NE) {
        const int d = dst[e];
        srcs[loff[d] + bases[d >> 10] + rank[e]] = src[e];
    }
}

// ---- bf16 MFMA GEMM + fused attn projections, with optional tail blocks ----
// TAIL=0: none. TAIL=1: scanA (chunk-local exclusive scan of t_cnt); last
//   finishing chunk scans bsum -> bases (device-scope done counter).
// TAIL=2: e-score writer for a PREVIOUS layer (H=4 float4 tables pel/per -> eout).
template <bool A_F32, int NT1, int NT2, int HH, int TAIL>
__global__ __launch_bounds__(256) void gemm_mfma(
    const void* __restrict__ Av, const bf16* __restrict__ B1t,
    const bf16* __restrict__ B2t,
    bf16* __restrict__ C1b, float* __restrict__ el, float* __restrict__ er,
    bf16* __restrict__ C2, int N, int K, int M, int nGemmBlocks,
    const int* __restrict__ t_cnt, int* __restrict__ t_loff, int* __restrict__ t_bsum,
    int* __restrict__ t_bases, int* __restrict__ t_done,
    const float4* __restrict__ pel, const float4* __restrict__ per,
    const int* __restrict__ src, const int* __restrict__ dst,
    float* __restrict__ eout) {
    constexpr int LP = 56;  // 32 k + pad: rows 112B (16B-aligned, 2-way alias = free)
    __shared__ bf16 As[64][LP];
    __shared__ bf16 Bs1[NT1 * 16][LP];
    __shared__ bf16 Bs2[(NT2 > 0) ? NT2 * 16 : 1][LP];
    __shared__ int ws4[4];

    const int tid = threadIdx.x;

    if constexpr (TAIL == 1) {
        if (blockIdx.x >= nGemmBlocks) {
            // chunk-local exclusive scan: 256 threads x 4 elems
            const int chunk = blockIdx.x - nGemmBlocks;
            const int lane = tid & 63;
            const int wid = tid >> 6;
            const int g = chunk * SCAN_CHUNK + tid * 4;
            const int a0 = (g + 0 < NN) ? t_cnt[g + 0] : 0;
            const int a1 = (g + 1 < NN) ? t_cnt[g + 1] : 0;
            const int a2 = (g + 2 < NN) ? t_cnt[g + 2] : 0;
            const int a3 = (g + 3 < NN) ? t_cnt[g + 3] : 0;
            const int lsum = a0 + a1 + a2 + a3;
            int x = lsum;
            #pragma unroll
            for (int off = 1; off < 64; off <<= 1) {
                int y = __shfl_up(x, off);
                if (lane >= off) x += y;
            }
            if (lane == 63) ws4[wid] = x;
            __syncthreads();
            int wbase = 0;
            #pragma unroll
            for (int j = 0; j < 4; ++j) if (j < wid) wbase += ws4[j];
            const int excl = wbase + x - lsum;
            if (g + 0 < NN) t_loff[g + 0] = excl;
            if (g + 1 < NN) t_loff[g + 1] = excl + a0;
            if (g + 2 < NN) t_loff[g + 2] = excl + a0 + a1;
            if (g + 3 < NN) t_loff[g + 3] = excl + a0 + a1 + a2;
            if (tid == 0) {
                t_bsum[chunk] = ws4[0] + ws4[1] + ws4[2] + ws4[3];
                __threadfence();                       // publish bsum + loff
                const int prev = atomicAdd(t_done, 1);
                if (prev == NCHUNKS - 1) {             // last chunk: scan bases
                    __threadfence();                   // acquire others' bsum
                    int acc = 0;
                    for (int j = 0; j < NCHUNKS; ++j) { t_bases[j] = acc; acc += t_bsum[j]; }
                    t_bases[NCHUNKS] = acc;
                }
            }
            return;
        }
    }
    if constexpr (TAIL == 2) {
        if (blockIdx.x >= nGemmBlocks) {
            const int e = (blockIdx.x - nGemmBlocks) * 256 + tid;  // exact NE grid
            const int s = src[e], d = dst[e];
            const float4 a = pel[s], b = per[d];
            float4 v;
            v.x = lrelu(a.x + b.x); v.y = lrelu(a.y + b.y);
            v.z = lrelu(a.z + b.z); v.w = lrelu(a.w + b.w);
            *reinterpret_cast<float4*>(eout + e * 4) = v;
            return;
        }
    }

    const int lane = tid & 63;
    const int wid = tid >> 6;
    const int row0 = blockIdx.x * 64;
    const int l15 = lane & 15;
    const int kq = lane >> 4;          // k-quarter 0..3

    f32x4 acc1[NT1], acc2[(NT2 > 0) ? NT2 : 1];
    #pragma unroll
    for (int t = 0; t < NT1; ++t) acc1[t] = (f32x4){0.f, 0.f, 0.f, 0.f};
    if constexpr (NT2 > 0) {
        #pragma unroll
        for (int t = 0; t < NT2; ++t) acc2[t] = (f32x4){0.f, 0.f, 0.f, 0.f};
    }

    for (int k0 = 0; k0 < K; k0 += 32) {
        {
            const int r = tid >> 2, kk = (tid & 3) * 8;
            const int gr = row0 + r;
            if constexpr (A_F32) {
                const float* A = (const float*)Av;
                short tmp[8];
                if (gr < N) {
                    const float4 v0 = *(const float4*)&A[(long)gr * K + k0 + kk];
                    const float4 v1 = *(const float4*)&A[(long)gr * K + k0 + kk + 4];
                    tmp[0] = f2bf(v0.x); tmp[1] = f2bf(v0.y); tmp[2] = f2bf(v0.z); tmp[3] = f2bf(v0.w);
                    tmp[4] = f2bf(v1.x); tmp[5] = f2bf(v1.y); tmp[6] = f2bf(v1.z); tmp[7] = f2bf(v1.w);
                } else {
                    #pragma unroll
                    for (int j = 0; j < 8; ++j) tmp[j] = 0;
                }
                *(frag_ab*)&As[r][kk] = *(const frag_ab*)tmp;
            } else {
                const bf16* A = (const bf16*)Av;
                frag_ab v = {0, 0, 0, 0, 0, 0, 0, 0};
                if (gr < N) v = *(const frag_ab*)&A[(long)gr * K + k0 + kk];
                *(frag_ab*)&As[r][kk] = v;
            }
        }
        for (int i = tid; i < NT1 * 64; i += 256) {
            const int c = i >> 2, kk = (i & 3) * 8;
            *(frag_ab*)&Bs1[c][kk] = *(const frag_ab*)&B1t[(long)c * K + k0 + kk];
        }
        if constexpr (NT2 > 0) {
            for (int i = tid; i < NT2 * 64; i += 256) {
                const int c = i >> 2, kk = (i & 3) * 8;
                *(frag_ab*)&Bs2[c][kk] = *(const frag_ab*)&B2t[(long)c * K + k0 + kk];
            }
        }
        __syncthreads();

        const frag_ab a = *(const frag_ab*)&As[wid * 16 + l15][kq * 8];
        #pragma unroll
        for (int t = 0; t < NT1; ++t) {
            const frag_ab b = *(const frag_ab*)&Bs1[t * 16 + l15][kq * 8];
            acc1[t] = __builtin_amdgcn_mfma_f32_16x16x32_bf16(a, b, acc1[t], 0, 0, 0);
        }
        if constexpr (NT2 > 0) {
            #pragma unroll
            for (int t = 0; t < NT2; ++t) {
                const frag_ab b = *(const frag_ab*)&Bs2[t * 16 + l15][kq * 8];
                acc2[t] = __builtin_amdgcn_mfma_f32_16x16x32_bf16(a, b, acc2[t], 0, 0, 0);
            }
        }
        __syncthreads();
    }

    const int r0 = row0 + wid * 16 + kq * 4;
    #pragma unroll
    for (int t = 0; t < NT1; ++t) {
        const int c = t * 16 + l15;
        #pragma unroll
        for (int reg = 0; reg < 4; ++reg) {
            const int r = r0 + reg;
            if (r >= N) continue;
            const float v = acc1[t][reg];
            if (c < M) {
                C1b[(long)r * M + c] = __float2bfloat16(v);
            } else if (c < M + HH) {
                el[(long)r * HH + (c - M)] = v;
            } else if (c < M + 2 * HH) {
                er[(long)r * HH + (c - M - HH)] = v;
            }
        }
    }
    if constexpr (NT2 > 0) {
        #pragma unroll
        for (int t = 0; t < NT2; ++t) {
            const int c = t * 16 + l15;
            if (c >= M) continue;
            #pragma unroll
            for (int reg = 0; reg < 4; ++reg) {
                const int r = r0 + reg;
                if (r < N) C2[(long)r * M + c] = __float2bfloat16(acc2[t][reg]);
            }
        }
    }
}

// ---- node softmax + aggregation, SINGLE PASS, one wave/node, H=4 D=32 ----
// Quarter-wave per edge: each edge is owned by exactly one quarter (16 lanes),
// which computes w = exp(lrelu(el[sn][h]+er[node][h])) inline (one wave-instr
// per 4 edges — not the 64-lane-redundant R6 trap) and gathers the 256B feat
// row as 16x ushort8. Per-lane partial s reduces with the same shfl butterfly
// as the accumulators; normalization folds into the epilogue.
template <int NELU, bool HAS_RES>
__global__ __launch_bounds__(256) void node_agg4(
    const bf16* __restrict__ featb, const float* __restrict__ el,
    const float4* __restrict__ er4,
    const int* __restrict__ loff, const int* __restrict__ bases,
    const int* __restrict__ srcs,
    const bf16* __restrict__ res, bf16* __restrict__ out) {
    const int node = (int)((blockIdx.x * blockDim.x + threadIdx.x) >> 6);
    const int lane = threadIdx.x & 63;
    const int beg = loff[node] + bases[node >> 10];
    const int end = (node == NN - 1) ? NE : loff[node + 1] + bases[(node + 1) >> 10];

    const int q = lane >> 4;          // quarter 0..3 (edge slot)
    const int l15 = lane & 15;
    const int fi = l15 * 8;           // 8 consecutive features (same head: 8|32)
    const int h = l15 >> 2;           // fi / 32
    const float4 ern4 = er4[node];    // wave-uniform
    const float ern = (h == 0) ? ern4.x : (h == 1) ? ern4.y : (h == 2) ? ern4.z : ern4.w;

    float a[8] = {0.f, 0.f, 0.f, 0.f, 0.f, 0.f, 0.f, 0.f};
    float sl = 0.f;
    int i = beg + q;
    for (; i + 4 < end; i += 8) {
        const int iB = i + 4;
        const int snA = srcs[i], snB = srcs[iB];
        const float wA = expw(el[snA * 4 + h] + ern);
        const float wB = expw(el[snB * 4 + h] + ern);
        sl += wA + wB;
        const frag_ab fA = *(const frag_ab*)(featb + (long)snA * 128 + fi);
        const frag_ab fB = *(const frag_ab*)(featb + (long)snB * 128 + fi);
        #pragma unroll
        for (int j = 0; j < 8; ++j)
            a[j] += wA * b2f((unsigned short)fA[j]) + wB * b2f((unsigned short)fB[j]);
    }
    for (; i < end; i += 4) {
        const int sn = srcs[i];
        const float w = expw(el[sn * 4 + h] + ern);
        sl += w;
        const frag_ab f = *(const frag_ab*)(featb + (long)sn * 128 + fi);
        #pragma unroll
        for (int j = 0; j < 8; ++j) a[j] += w * b2f((unsigned short)f[j]);
    }
    // reduce s and accumulators over the 4 quarters
    sl += __shfl_xor(sl, 16);
    sl += __shfl_xor(sl, 32);
    #pragma unroll
    for (int j = 0; j < 8; ++j) {
        a[j] += __shfl_xor(a[j], 16);
        a[j] += __shfl_xor(a[j], 32);
    }

    if (lane < 16) {
        const float inv = 1.f / fmaxf(sl, 1e-9f);
        float v[8];
        #pragma unroll
        for (int j = 0; j < 8; ++j) v[j] = a[j] * inv;
        if constexpr (HAS_RES) {
            const frag_ab rr = *(const frag_ab*)(res + (long)node * 128 + fi);
            #pragma unroll
            for (int j = 0; j < 8; ++j) v[j] += b2f((unsigned short)rr[j]);
        }
        #pragma unroll
        for (int t = 0; t < NELU; ++t)
            #pragma unroll
            for (int j = 0; j < 8; ++j)
                v[j] = (v[j] > 0.f) ? v[j] : expm1f(v[j]);
        frag_ab o;
        #pragma unroll
        for (int j = 0; j < 8; ++j) o[j] = f2bf(v[j]);
        *(frag_ab*)(out + (long)node * 128 + fi) = o;
    }
}

// ---- final fused kernel: node_agg1 (blocks < NODE_BLKS) + e2 writes ----
__global__ __launch_bounds__(256) void final_k(
    const bf16* __restrict__ featb, const float* __restrict__ el2s,
    const float* __restrict__ er2s, float* __restrict__ es1,
    const int* __restrict__ loff, const int* __restrict__ bases,
    const int* __restrict__ srcs,
    const bf16* __restrict__ res, float* __restrict__ logits,
    const int* __restrict__ src, const int* __restrict__ dst,
    float* __restrict__ e2) {
    __shared__ float sc1[4][64];      // per-wave score cache (1 KB)
    if (blockIdx.x < NODE_BLKS) {
        const int node = (int)((blockIdx.x * blockDim.x + threadIdx.x) >> 6);
        const int lane = threadIdx.x & 63;
        const int wid = threadIdx.x >> 6;
        const int beg = loff[node] + bases[node >> 10];
        const int end = (node == NN - 1) ? NE : loff[node + 1] + bases[(node + 1) >> 10];
        const float ern = er2s[node];

        float s = 0.f;
        for (int i = beg + lane; i < end; i += 64) {
            const float t = expw(el2s[srcs[i]] + ern);
            s += t;
            const int idx = i - beg;
            if (idx < 64) sc1[wid][idx] = t;
            else es1[i] = t;
        }
        #pragma unroll
        for (int off = 32; off > 0; off >>= 1) s += __shfl_xor(s, off);
        const float inv = 1.f / fmaxf(s, 1e-9f);
        __syncthreads();

        // aggregation with 8-deep unroll (8 gathers in flight)
        const bool active = lane < NC;
        float acc = 0.f;
        int i = beg;
        for (; i + 8 <= end; i += 8) {
            const int d0 = i - beg;
            int sn[8]; float w[8];
            #pragma unroll
            for (int k = 0; k < 8; ++k) {
                sn[k] = srcs[i + k];
                w[k] = (d0 + k < 64) ? sc1[wid][d0 + k] : es1[i + k];
            }
            if (active) {
                #pragma unroll
                for (int k = 0; k < 8; ++k)
                    acc += w[k] * __bfloat162float(featb[(long)sn[k] * NC + lane]);
            }
        }
        for (; i < end; ++i) {
            const int idx = i - beg;
            const float w = (idx < 64) ? sc1[wid][idx] : es1[i];
            if (active) acc += w * __bfloat162float(featb[(long)srcs[i] * NC + lane]);
        }
        if (active) {
            logits[(long)node * NC + lane] =
                acc * inv + __bfloat162float(res[(long)node * NC + lane]);
        }
    } else {
        const int e = (blockIdx.x - NODE_BLKS) * 256 + threadIdx.x;  // exact NE
        e2[e] = lrelu(el2s[src[e]] + er2s[dst[e]]);
    }
}

extern "C" void kernel_launch(void* const* d_in, const int* in_sizes, int n_in,
                              void* d_out, int out_size, void* d_ws, size_t ws_size,
                              hipStream_t stream) {
    const float* x     = (const float*)d_in[0];
    const float* W0    = (const float*)d_in[1];
    const float* al0   = (const float*)d_in[2];
    const float* ar0   = (const float*)d_in[3];
    const float* W1    = (const float*)d_in[4];
    const float* resW1 = (const float*)d_in[5];
    const float* al1   = (const float*)d_in[6];
    const float* ar1   = (const float*)d_in[7];
    const float* W2    = (const float*)d_in[8];
    const float* resW2 = (const float*)d_in[9];
    const float* al2   = (const float*)d_in[10];
    const float* ar2   = (const float*)d_in[11];
    const int*   src   = (const int*)d_in[12];
    const int*   dst   = (const int*)d_in[13];

    float* out    = (float*)d_out;
    float* logits = out;                 // [N, 47]
    float* e0     = out + (long)NN * NC; // [E, 4]
    float* e1     = e0 + (long)NE * NH;  // [E, 4]
    float* e2     = e1 + (long)NE * NH;  // [E, 1]

    char* p = (char*)d_ws;
    int* cnt    = (int*)p; p += align256(sizeof(int) * (NN + 64));  // cnt + done ctr
    int* done   = cnt + NN;
    int* loff   = (int*)p; p += align256(sizeof(int) * (NN + 1));
    int* bsum   = (int*)p; p += align256(sizeof(int) * 32);
    int* bases  = (int*)p; p += align256(sizeof(int) * 32);
    int* rank   = (int*)p; p += align256(sizeof(int) * NE);
    int* srcs   = (int*)p; p += align256(sizeof(int) * NE);
    float* el0b = (float*)p; p += align256(sizeof(float) * NN * NH);
    float* er0b = (float*)p; p += align256(sizeof(float) * NN * NH);
    float* el1b = (float*)p; p += align256(sizeof(float) * NN * NH);
    float* er1b = (float*)p; p += align256(sizeof(float) * NN * NH);
    float* el2b = (float*)p; p += align256(sizeof(float) * NN);
    float* er2b = (float*)p; p += align256(sizeof(float) * NN);
    float* es   = (float*)p; p += align256(sizeof(float) * NE);  // final_k spill only
    bf16* resb  = (bf16*)p; p += align256(sizeof(bf16) * (long)NN * 128);
    bf16* featb = (bf16*)p; p += align256(sizeof(bf16) * (long)NN * 128);
    bf16* hb    = (bf16*)p; p += align256(sizeof(bf16) * (long)NN * 128);
    bf16* W0t   = (bf16*)p; p += align256(sizeof(bf16) * 144 * 256);
    bf16* W1t   = (bf16*)p; p += align256(sizeof(bf16) * 144 * 128);
    bf16* rW1t  = (bf16*)p; p += align256(sizeof(bf16) * 128 * 128);
    bf16* W2t   = (bf16*)p; p += align256(sizeof(bf16) * 64 * 128);
    bf16* rW2t  = (bf16*)p; p += align256(sizeof(bf16) * 48 * 128);

    const int gemmBlocks = (NN + 63) / 64;   // 469

    // ---- 1: zero cnt+done; 2: prep weights ∥ count+rank ----
    hipMemsetAsync(cnt, 0, sizeof(int) * (NN + 64), stream);
    prep_count<<<dim3(EDGE_BLKS, 6), 256, 0, stream>>>(
        W0, W1, resW1, W2, resW2, al0, ar0, al1, ar1, al2, ar2,
        W0t, W1t, rW1t, W2t, rW2t, dst, cnt, rank);

    // ---- 3: gemm0 ∥ scanA (chunk scans + bases, hidden under layer-0 GEMM) ----
    gemm_mfma<true, 9, 0, NH, 1><<<gemmBlocks + NCHUNKS, 256, 0, stream>>>(
        x, W0t, nullptr, featb, el0b, er0b, nullptr, NN, FIN, 128, gemmBlocks,
        cnt, loff, bsum, bases, done, nullptr, nullptr, nullptr, nullptr, nullptr);

    // ---- 4: fill (atomic-free, rank-based) ----
    fill_k<<<EDGE_BLKS, 256, 0, stream>>>(dst, src, rank, loff, bases, srcs);

    // ---- 5: layer-0 aggregation (single pass) ----
    node_agg4<1, false><<<NODE_BLKS, 256, 0, stream>>>(
        featb, el0b, (const float4*)er0b, loff, bases, srcs, nullptr, hb);

    // ---- 6: gemm1 (dual) ∥ e0 writes ----
    gemm_mfma<false, 9, 8, NH, 2><<<gemmBlocks + EDGE_BLKS, 256, 0, stream>>>(
        hb, W1t, rW1t, featb, el1b, er1b, resb, NN, 128, 128, gemmBlocks,
        nullptr, nullptr, nullptr, nullptr, nullptr,
        (const float4*)el0b, (const float4*)er0b, src, dst, e0);

    // ---- 7: layer-1 aggregation (single pass) ----
    node_agg4<2, true><<<NODE_BLKS, 256, 0, stream>>>(
        featb, el1b, (const float4*)er1b, loff, bases, srcs, resb, hb);

    // ---- 8: gemm2 (dual, M=47) ∥ e1 writes ----
    gemm_mfma<false, 4, 3, 1, 2><<<gemmBlocks + EDGE_BLKS, 256, 0, stream>>>(
        hb, W2t, rW2t, featb, el2b, er2b, resb, NN, 128, NC, gemmBlocks,
        nullptr, nullptr, nullptr, nullptr, nullptr,
        (const float4*)el1b, (const float4*)er1b, src, dst, e1);

    // ---- 9: node_agg1 (logits) ∥ e2 writes ----
    final_k<<<NODE_BLKS + EDGE_BLKS, 256, 0, stream>>>(
        featb, el2b, er2b, es, loff, bases, srcs, resb, logits, src, dst, e2);
}

// Round 15
// 176.536 us; speedup vs baseline: 1.4365x; 1.0085x over previous
//
#include <hip/hip_runtime.h>
#include <hip/hip_bf16.h>
#include <math.h>

// Problem constants
#define NN 30000
#define NE 480000
#define FIN 256
#define DH 32
#define NH 4
#define NC 47
#define NODE_BLKS 7500   // NN/4 (4 waves/block, 1 wave/node)
#define EDGE_BLKS 1875   // NE/256
#define SCAN_CHUNK 1024  // 30 chunks of 1024 (30720 >= 30000)
#define NCHUNKS 30

typedef __attribute__((ext_vector_type(8))) short frag_ab;  // 8 bf16 (4 VGPR)
typedef __attribute__((ext_vector_type(4))) float f32x4;    // MFMA 16x16 accum
typedef __hip_bfloat16 bf16;

static inline size_t align256(size_t x) { return (x + 255) & ~(size_t)255; }

__device__ __forceinline__ short f2bf(float f) {
    union { float f; unsigned u; } c; c.f = f;
    unsigned r = (c.u + 0x7FFFu + ((c.u >> 16) & 1u)) >> 16;  // RNE
    return (short)r;
}
__device__ __forceinline__ float b2f(unsigned short u) {
    union { unsigned u; float f; } c; c.u = (unsigned)u << 16; return c.f;
}
// exp(leaky_relu(v)) — no max subtraction (scores O(10), far from f32 overflow)
__device__ __forceinline__ float expw(float v) {
    return __expf((v >= 0.f) ? v : 0.2f * v);
}
__device__ __forceinline__ float lrelu(float v) {
    return (v >= 0.f) ? v : 0.2f * v;
}

// ---- weight prep (y<5) ∥ CSR count+rank (y==5). cnt zeroed beforehand.
// rank[e] = this edge's arrival index among edges with the same dst.
// Layout: rows 0..Msrc-1 = W^T; rows Mpad..Mpad+H-1 = W·al; next H = W·ar; rest 0.
// (For gemm2: Msrc=47, Mpad=48 -> row 47 is a zero pad column.)
__global__ void prep_count(const float* __restrict__ W0, const float* __restrict__ W1,
                           const float* __restrict__ rW1, const float* __restrict__ W2,
                           const float* __restrict__ rW2,
                           const float* __restrict__ al0, const float* __restrict__ ar0,
                           const float* __restrict__ al1, const float* __restrict__ ar1,
                           const float* __restrict__ al2, const float* __restrict__ ar2,
                           bf16* __restrict__ W0t, bf16* __restrict__ W1t,
                           bf16* __restrict__ rW1t, bf16* __restrict__ W2t,
                           bf16* __restrict__ rW2t,
                           const int* __restrict__ dst, int* __restrict__ cnt,
                           int* __restrict__ rank) {
    if (blockIdx.y == 5) {   // edge count + rank
        int e = blockIdx.x * 256 + threadIdx.x;
        if (e < NE) rank[e] = atomicAdd(&cnt[dst[e]], 1);
        return;
    }
    const float *W, *al, *ar; bf16* Wt; int K, Msrc, Mpad, rows, H, D;
    switch (blockIdx.y) {
        case 0: W = W0;  Wt = W0t;  K = 256; Msrc = 128; Mpad = 128; rows = 144; H = 4; D = 32; al = al0; ar = ar0; break;
        case 1: W = W1;  Wt = W1t;  K = 128; Msrc = 128; Mpad = 128; rows = 144; H = 4; D = 32; al = al1; ar = ar1; break;
        case 2: W = rW1; Wt = rW1t; K = 128; Msrc = 128; Mpad = 128; rows = 128; H = 0; D = 0;  al = nullptr; ar = nullptr; break;
        case 3: W = W2;  Wt = W2t;  K = 128; Msrc = 47;  Mpad = 48;  rows = 64;  H = 1; D = 47; al = al2; ar = ar2; break;
        default: W = rW2; Wt = rW2t; K = 128; Msrc = 47; Mpad = 48;  rows = 48;  H = 0; D = 0;  al = nullptr; ar = nullptr; break;
    }
    int i = blockIdx.x * 256 + threadIdx.x;
    if (i >= rows * K) return;
    int row = i / K, k = i - row * K;
    float v = 0.f;
    if (row < Msrc) {
        v = W[(long)k * Msrc + row];
    } else if (H > 0 && row >= Mpad && row < Mpad + 2 * H) {
        int idx = row - Mpad;
        int h = (idx < H) ? idx : idx - H;
        const float* a = (idx < H) ? al : ar;
        float s = 0.f;
        for (int d = 0; d < D; ++d) s += W[(long)k * Msrc + h * D + d] * a[h * D + d];
        v = s;
    }
    Wt[i] = __float2bfloat16(v);
}

// srcs[slot] = src id, in CSR-by-dst order. Atomic-free (rank precomputed).
__global__ void fill_k(const int* __restrict__ dst, const int* __restrict__ src,
                       const int* __restrict__ rank, const int* __restrict__ loff,
                       const int* __restrict__ bases, int* __restrict__ srcs) {
    int e = blockIdx.x * blockDim.x + threadIdx.x;
    if (e < NE) {
        const int d = dst[e];
        srcs[loff[d] + bases[d >> 10] + rank[e]] = src[e];
    }
}

// ---- bf16 MFMA GEMM + fused attn projections, with optional tail blocks ----
// TAIL=0: none. TAIL=1: scanA (chunk-local exclusive scan of t_cnt); last
//   finishing chunk scans bsum -> bases (device-scope done counter).
// TAIL=2: e-score writer for a PREVIOUS layer (H=4 float4 tables pel/per -> eout).
template <bool A_F32, int NT1, int NT2, int HH, int TAIL>
__global__ __launch_bounds__(256) void gemm_mfma(
    const void* __restrict__ Av, const bf16* __restrict__ B1t,
    const bf16* __restrict__ B2t,
    bf16* __restrict__ C1b, float* __restrict__ el, float* __restrict__ er,
    bf16* __restrict__ C2, int N, int K, int M, int nGemmBlocks,
    const int* __restrict__ t_cnt, int* __restrict__ t_loff, int* __restrict__ t_bsum,
    int* __restrict__ t_bases, int* __restrict__ t_done,
    const float4* __restrict__ pel, const float4* __restrict__ per,
    const int* __restrict__ src, const int* __restrict__ dst,
    float* __restrict__ eout) {
    constexpr int LP = 56;  // 32 k + pad: rows 112B (16B-aligned, 2-way alias = free)
    __shared__ bf16 As[64][LP];
    __shared__ bf16 Bs1[NT1 * 16][LP];
    __shared__ bf16 Bs2[(NT2 > 0) ? NT2 * 16 : 1][LP];
    __shared__ int ws4[4];

    const int tid = threadIdx.x;

    if constexpr (TAIL == 1) {
        if (blockIdx.x >= nGemmBlocks) {
            // chunk-local exclusive scan: 256 threads x 4 elems
            const int chunk = blockIdx.x - nGemmBlocks;
            const int lane = tid & 63;
            const int wid = tid >> 6;
            const int g = chunk * SCAN_CHUNK + tid * 4;
            const int a0 = (g + 0 < NN) ? t_cnt[g + 0] : 0;
            const int a1 = (g + 1 < NN) ? t_cnt[g + 1] : 0;
            const int a2 = (g + 2 < NN) ? t_cnt[g + 2] : 0;
            const int a3 = (g + 3 < NN) ? t_cnt[g + 3] : 0;
            const int lsum = a0 + a1 + a2 + a3;
            int x = lsum;
            #pragma unroll
            for (int off = 1; off < 64; off <<= 1) {
                int y = __shfl_up(x, off);
                if (lane >= off) x += y;
            }
            if (lane == 63) ws4[wid] = x;
            __syncthreads();
            int wbase = 0;
            #pragma unroll
            for (int j = 0; j < 4; ++j) if (j < wid) wbase += ws4[j];
            const int excl = wbase + x - lsum;
            if (g + 0 < NN) t_loff[g + 0] = excl;
            if (g + 1 < NN) t_loff[g + 1] = excl + a0;
            if (g + 2 < NN) t_loff[g + 2] = excl + a0 + a1;
            if (g + 3 < NN) t_loff[g + 3] = excl + a0 + a1 + a2;
            if (tid == 0) {
                t_bsum[chunk] = ws4[0] + ws4[1] + ws4[2] + ws4[3];
                __threadfence();                       // publish bsum + loff
                const int prev = atomicAdd(t_done, 1);
                if (prev == NCHUNKS - 1) {             // last chunk: scan bases
                    __threadfence();                   // acquire others' bsum
                    int acc = 0;
                    for (int j = 0; j < NCHUNKS; ++j) { t_bases[j] = acc; acc += t_bsum[j]; }
                    t_bases[NCHUNKS] = acc;
                }
            }
            return;
        }
    }
    if constexpr (TAIL == 2) {
        if (blockIdx.x >= nGemmBlocks) {
            const int e = (blockIdx.x - nGemmBlocks) * 256 + tid;  // exact NE grid
            const int s = src[e], d = dst[e];
            const float4 a = pel[s], b = per[d];
            float4 v;
            v.x = lrelu(a.x + b.x); v.y = lrelu(a.y + b.y);
            v.z = lrelu(a.z + b.z); v.w = lrelu(a.w + b.w);
            *reinterpret_cast<float4*>(eout + e * 4) = v;
            return;
        }
    }

    const int lane = tid & 63;
    const int wid = tid >> 6;
    const int row0 = blockIdx.x * 64;
    const int l15 = lane & 15;
    const int kq = lane >> 4;          // k-quarter 0..3

    f32x4 acc1[NT1], acc2[(NT2 > 0) ? NT2 : 1];
    #pragma unroll
    for (int t = 0; t < NT1; ++t) acc1[t] = (f32x4){0.f, 0.f, 0.f, 0.f};
    if constexpr (NT2 > 0) {
        #pragma unroll
        for (int t = 0; t < NT2; ++t) acc2[t] = (f32x4){0.f, 0.f, 0.f, 0.f};
    }

    for (int k0 = 0; k0 < K; k0 += 32) {
        {
            const int r = tid >> 2, kk = (tid & 3) * 8;
            const int gr = row0 + r;
            if constexpr (A_F32) {
                const float* A = (const float*)Av;
                short tmp[8];
                if (gr < N) {
                    const float4 v0 = *(const float4*)&A[(long)gr * K + k0 + kk];
                    const float4 v1 = *(const float4*)&A[(long)gr * K + k0 + kk + 4];
                    tmp[0] = f2bf(v0.x); tmp[1] = f2bf(v0.y); tmp[2] = f2bf(v0.z); tmp[3] = f2bf(v0.w);
                    tmp[4] = f2bf(v1.x); tmp[5] = f2bf(v1.y); tmp[6] = f2bf(v1.z); tmp[7] = f2bf(v1.w);
                } else {
                    #pragma unroll
                    for (int j = 0; j < 8; ++j) tmp[j] = 0;
                }
                *(frag_ab*)&As[r][kk] = *(const frag_ab*)tmp;
            } else {
                const bf16* A = (const bf16*)Av;
                frag_ab v = {0, 0, 0, 0, 0, 0, 0, 0};
                if (gr < N) v = *(const frag_ab*)&A[(long)gr * K + k0 + kk];
                *(frag_ab*)&As[r][kk] = v;
            }
        }
        for (int i = tid; i < NT1 * 64; i += 256) {
            const int c = i >> 2, kk = (i & 3) * 8;
            *(frag_ab*)&Bs1[c][kk] = *(const frag_ab*)&B1t[(long)c * K + k0 + kk];
        }
        if constexpr (NT2 > 0) {
            for (int i = tid; i < NT2 * 64; i += 256) {
                const int c = i >> 2, kk = (i & 3) * 8;
                *(frag_ab*)&Bs2[c][kk] = *(const frag_ab*)&B2t[(long)c * K + k0 + kk];
            }
        }
        __syncthreads();

        const frag_ab a = *(const frag_ab*)&As[wid * 16 + l15][kq * 8];
        #pragma unroll
        for (int t = 0; t < NT1; ++t) {
            const frag_ab b = *(const frag_ab*)&Bs1[t * 16 + l15][kq * 8];
            acc1[t] = __builtin_amdgcn_mfma_f32_16x16x32_bf16(a, b, acc1[t], 0, 0, 0);
        }
        if constexpr (NT2 > 0) {
            #pragma unroll
            for (int t = 0; t < NT2; ++t) {
                const frag_ab b = *(const frag_ab*)&Bs2[t * 16 + l15][kq * 8];
                acc2[t] = __builtin_amdgcn_mfma_f32_16x16x32_bf16(a, b, acc2[t], 0, 0, 0);
            }
        }
        __syncthreads();
    }

    const int r0 = row0 + wid * 16 + kq * 4;
    #pragma unroll
    for (int t = 0; t < NT1; ++t) {
        const int c = t * 16 + l15;
        #pragma unroll
        for (int reg = 0; reg < 4; ++reg) {
            const int r = r0 + reg;
            if (r >= N) continue;
            const float v = acc1[t][reg];
            if (c < M) {
                C1b[(long)r * M + c] = __float2bfloat16(v);
            } else if (c < M + HH) {
                el[(long)r * HH + (c - M)] = v;
            } else if (c < M + 2 * HH) {
                er[(long)r * HH + (c - M - HH)] = v;
            }
        }
    }
    if constexpr (NT2 > 0) {
        #pragma unroll
        for (int t = 0; t < NT2; ++t) {
            const int c = t * 16 + l15;
            if (c >= M) continue;
            #pragma unroll
            for (int reg = 0; reg < 4; ++reg) {
                const int r = r0 + reg;
                if (r < N) C2[(long)r * M + c] = __float2bfloat16(acc2[t][reg]);
            }
        }
    }
}

// ---- node softmax + aggregation, SINGLE PASS, one wave/node, H=4 D=32 ----
// Quarter-wave per edge; score computed inline (one wave-instr per 4 edges).
template <int NELU, bool HAS_RES>
__global__ __launch_bounds__(256) void node_agg4(
    const bf16* __restrict__ featb, const float* __restrict__ el,
    const float4* __restrict__ er4,
    const int* __restrict__ loff, const int* __restrict__ bases,
    const int* __restrict__ srcs,
    const bf16* __restrict__ res, bf16* __restrict__ out) {
    const int node = (int)((blockIdx.x * blockDim.x + threadIdx.x) >> 6);
    const int lane = threadIdx.x & 63;
    const int beg = loff[node] + bases[node >> 10];
    const int end = (node == NN - 1) ? NE : loff[node + 1] + bases[(node + 1) >> 10];

    const int q = lane >> 4;          // quarter 0..3 (edge slot)
    const int l15 = lane & 15;
    const int fi = l15 * 8;           // 8 consecutive features (same head: 8|32)
    const int h = l15 >> 2;           // fi / 32
    const float4 ern4 = er4[node];    // wave-uniform
    const float ern = (h == 0) ? ern4.x : (h == 1) ? ern4.y : (h == 2) ? ern4.z : ern4.w;

    float a[8] = {0.f, 0.f, 0.f, 0.f, 0.f, 0.f, 0.f, 0.f};
    float sl = 0.f;
    int i = beg + q;
    for (; i + 4 < end; i += 8) {
        const int iB = i + 4;
        const int snA = srcs[i], snB = srcs[iB];
        const float wA = expw(el[snA * 4 + h] + ern);
        const float wB = expw(el[snB * 4 + h] + ern);
        sl += wA + wB;
        const frag_ab fA = *(const frag_ab*)(featb + (long)snA * 128 + fi);
        const frag_ab fB = *(const frag_ab*)(featb + (long)snB * 128 + fi);
        #pragma unroll
        for (int j = 0; j < 8; ++j)
            a[j] += wA * b2f((unsigned short)fA[j]) + wB * b2f((unsigned short)fB[j]);
    }
    for (; i < end; i += 4) {
        const int sn = srcs[i];
        const float w = expw(el[sn * 4 + h] + ern);
        sl += w;
        const frag_ab f = *(const frag_ab*)(featb + (long)sn * 128 + fi);
        #pragma unroll
        for (int j = 0; j < 8; ++j) a[j] += w * b2f((unsigned short)f[j]);
    }
    // reduce s and accumulators over the 4 quarters
    sl += __shfl_xor(sl, 16);
    sl += __shfl_xor(sl, 32);
    #pragma unroll
    for (int j = 0; j < 8; ++j) {
        a[j] += __shfl_xor(a[j], 16);
        a[j] += __shfl_xor(a[j], 32);
    }

    if (lane < 16) {
        const float inv = 1.f / fmaxf(sl, 1e-9f);
        float v[8];
        #pragma unroll
        for (int j = 0; j < 8; ++j) v[j] = a[j] * inv;
        if constexpr (HAS_RES) {
            const frag_ab rr = *(const frag_ab*)(res + (long)node * 128 + fi);
            #pragma unroll
            for (int j = 0; j < 8; ++j) v[j] += b2f((unsigned short)rr[j]);
        }
        #pragma unroll
        for (int t = 0; t < NELU; ++t)
            #pragma unroll
            for (int j = 0; j < 8; ++j)
                v[j] = (v[j] > 0.f) ? v[j] : expm1f(v[j]);
        frag_ab o;
        #pragma unroll
        for (int j = 0; j < 8; ++j) o[j] = f2bf(v[j]);
        *(frag_ab*)(out + (long)node * 128 + fi) = o;
    }
}

// ---- final fused kernel: node_agg1 single-pass (blocks < NODE_BLKS) + e2 ----
// Node branch: half-wave per edge; 24 active lanes x ushort2 cover the padded
// 48-feature row (feature 47 == 0 pad). Score inline per half; s is
// lane-uniform within a half -> total = shfl(s,0)+shfl(s,32).
__global__ __launch_bounds__(256) void final_k(
    const bf16* __restrict__ featb48, const float* __restrict__ el2s,
    const float* __restrict__ er2s,
    const int* __restrict__ loff, const int* __restrict__ bases,
    const int* __restrict__ srcs,
    const bf16* __restrict__ res48, float* __restrict__ logits,
    const int* __restrict__ src, const int* __restrict__ dst,
    float* __restrict__ e2) {
    if (blockIdx.x < NODE_BLKS) {
        const int node = (int)((blockIdx.x * blockDim.x + threadIdx.x) >> 6);
        const int lane = threadIdx.x & 63;
        const int beg = loff[node] + bases[node >> 10];
        const int end = (node == NN - 1) ? NE : loff[node + 1] + bases[(node + 1) >> 10];
        const float ern = er2s[node];

        const int half = lane >> 5;   // 0/1: edge slot
        const int l31 = lane & 31;
        const bool act = l31 < 24;    // 24 lanes x 2 features = 48 (feature 47 = pad)
        const int fi = l31 * 2;

        float a0 = 0.f, a1 = 0.f, sl = 0.f;
        int i = beg + half;
        for (; i + 2 < end; i += 4) {
            const int iB = i + 2;
            const int snA = srcs[i], snB = srcs[iB];
            const float wA = expw(el2s[snA] + ern);
            const float wB = expw(el2s[snB] + ern);
            sl += wA + wB;
            if (act) {
                const ushort2 fA = *(const ushort2*)(featb48 + (long)snA * 48 + fi);
                const ushort2 fB = *(const ushort2*)(featb48 + (long)snB * 48 + fi);
                a0 += wA * b2f(fA.x) + wB * b2f(fB.x);
                a1 += wA * b2f(fA.y) + wB * b2f(fB.y);
            }
        }
        for (; i < end; i += 2) {
            const int sn = srcs[i];
            const float w = expw(el2s[sn] + ern);
            sl += w;
            if (act) {
                const ushort2 f = *(const ushort2*)(featb48 + (long)sn * 48 + fi);
                a0 += w * b2f(f.x);
                a1 += w * b2f(f.y);
            }
        }
        // total s: sl is identical across lanes within a half
        const float s = __shfl(sl, 0) + __shfl(sl, 32);
        a0 += __shfl_xor(a0, 32);
        a1 += __shfl_xor(a1, 32);

        if (lane < 24) {
            const float inv = 1.f / fmaxf(s, 1e-9f);
            const ushort2 rr = *(const ushort2*)(res48 + (long)node * 48 + fi);
            const float v0 = a0 * inv + b2f(rr.x);
            const float v1 = a1 * inv + b2f(rr.y);
            logits[(long)node * NC + fi] = v0;
            if (fi + 1 < NC) logits[(long)node * NC + fi + 1] = v1;
        }
    } else {
        const int e = (blockIdx.x - NODE_BLKS) * 256 + threadIdx.x;  // exact NE
        e2[e] = lrelu(el2s[src[e]] + er2s[dst[e]]);
    }
}

extern "C" void kernel_launch(void* const* d_in, const int* in_sizes, int n_in,
                              void* d_out, int out_size, void* d_ws, size_t ws_size,
                              hipStream_t stream) {
    const float* x     = (const float*)d_in[0];
    const float* W0    = (const float*)d_in[1];
    const float* al0   = (const float*)d_in[2];
    const float* ar0   = (const float*)d_in[3];
    const float* W1    = (const float*)d_in[4];
    const float* resW1 = (const float*)d_in[5];
    const float* al1   = (const float*)d_in[6];
    const float* ar1   = (const float*)d_in[7];
    const float* W2    = (const float*)d_in[8];
    const float* resW2 = (const float*)d_in[9];
    const float* al2   = (const float*)d_in[10];
    const float* ar2   = (const float*)d_in[11];
    const int*   src   = (const int*)d_in[12];
    const int*   dst   = (const int*)d_in[13];

    float* out    = (float*)d_out;
    float* logits = out;                 // [N, 47]
    float* e0     = out + (long)NN * NC; // [E, 4]
    float* e1     = e0 + (long)NE * NH;  // [E, 4]
    float* e2     = e1 + (long)NE * NH;  // [E, 1]

    char* p = (char*)d_ws;
    int* cnt    = (int*)p; p += align256(sizeof(int) * (NN + 64));  // cnt + done ctr
    int* done   = cnt + NN;
    int* loff   = (int*)p; p += align256(sizeof(int) * (NN + 1));
    int* bsum   = (int*)p; p += align256(sizeof(int) * 32);
    int* bases  = (int*)p; p += align256(sizeof(int) * 32);
    int* rank   = (int*)p; p += align256(sizeof(int) * NE);
    int* srcs   = (int*)p; p += align256(sizeof(int) * NE);
    float* el0b = (float*)p; p += align256(sizeof(float) * NN * NH);
    float* er0b = (float*)p; p += align256(sizeof(float) * NN * NH);
    float* el1b = (float*)p; p += align256(sizeof(float) * NN * NH);
    float* er1b = (float*)p; p += align256(sizeof(float) * NN * NH);
    float* el2b = (float*)p; p += align256(sizeof(float) * NN);
    float* er2b = (float*)p; p += align256(sizeof(float) * NN);
    bf16* resb  = (bf16*)p; p += align256(sizeof(bf16) * (long)NN * 128);
    bf16* featb = (bf16*)p; p += align256(sizeof(bf16) * (long)NN * 128);
    bf16* hb    = (bf16*)p; p += align256(sizeof(bf16) * (long)NN * 128);
    bf16* W0t   = (bf16*)p; p += align256(sizeof(bf16) * 144 * 256);
    bf16* W1t   = (bf16*)p; p += align256(sizeof(bf16) * 144 * 128);
    bf16* rW1t  = (bf16*)p; p += align256(sizeof(bf16) * 128 * 128);
    bf16* W2t   = (bf16*)p; p += align256(sizeof(bf16) * 64 * 128);
    bf16* rW2t  = (bf16*)p; p += align256(sizeof(bf16) * 48 * 128);

    const int gemmBlocks = (NN + 63) / 64;   // 469

    // ---- 1: zero cnt+done; 2: prep weights ∥ count+rank ----
    hipMemsetAsync(cnt, 0, sizeof(int) * (NN + 64), stream);
    prep_count<<<dim3(EDGE_BLKS, 6), 256, 0, stream>>>(
        W0, W1, resW1, W2, resW2, al0, ar0, al1, ar1, al2, ar2,
        W0t, W1t, rW1t, W2t, rW2t, dst, cnt, rank);

    // ---- 3: gemm0 ∥ scanA (chunk scans + bases, hidden under layer-0 GEMM) ----
    gemm_mfma<true, 9, 0, NH, 1><<<gemmBlocks + NCHUNKS, 256, 0, stream>>>(
        x, W0t, nullptr, featb, el0b, er0b, nullptr, NN, FIN, 128, gemmBlocks,
        cnt, loff, bsum, bases, done, nullptr, nullptr, nullptr, nullptr, nullptr);

    // ---- 4: fill (atomic-free, rank-based) ----
    fill_k<<<EDGE_BLKS, 256, 0, stream>>>(dst, src, rank, loff, bases, srcs);

    // ---- 5: layer-0 aggregation (single pass) ----
    node_agg4<1, false><<<NODE_BLKS, 256, 0, stream>>>(
        featb, el0b, (const float4*)er0b, loff, bases, srcs, nullptr, hb);

    // ---- 6: gemm1 (dual) ∥ e0 writes ----
    gemm_mfma<false, 9, 8, NH, 2><<<gemmBlocks + EDGE_BLKS, 256, 0, stream>>>(
        hb, W1t, rW1t, featb, el1b, er1b, resb, NN, 128, 128, gemmBlocks,
        nullptr, nullptr, nullptr, nullptr, nullptr,
        (const float4*)el0b, (const float4*)er0b, src, dst, e0);

    // ---- 7: layer-1 aggregation (single pass) ----
    node_agg4<2, true><<<NODE_BLKS, 256, 0, stream>>>(
        featb, el1b, (const float4*)er1b, loff, bases, srcs, resb, hb);

    // ---- 8: gemm2 (dual, padded M=48) ∥ e1 writes ----
    // W2t: rows 0..46 = W2^T, row 47 = 0, rows 48/49 = W2·al2 / W2·ar2.
    // featb/resb written at stride 48 (col 47 exactly 0 from zero weight rows).
    gemm_mfma<false, 4, 3, 1, 2><<<gemmBlocks + EDGE_BLKS, 256, 0, stream>>>(
        hb, W2t, rW2t, featb, el2b, er2b, resb, NN, 128, 48, gemmBlocks,
        nullptr, nullptr, nullptr, nullptr, nullptr,
        (const float4*)el1b, (const float4*)er1b, src, dst, e1);

    // ---- 9: node_agg1 single-pass (logits) ∥ e2 writes ----
    final_k<<<NODE_BLKS + EDGE_BLKS, 256, 0, stream>>>(
        featb, el2b, er2b, loff, bases, srcs, resb, logits, src, dst, e2);
}